// Round 5
// baseline (1273.051 us; speedup 1.0000x reference)
//
#include <hip/hip_runtime.h>
#include <hip/hip_bf16.h>

#define SEQ    512
#define DMODEL 512
#define NHEAD  8
#define DK     64
#define BS     16
#define NBH    (BS*NHEAD)       // 128
#define HSZ    (SEQ*DK)         // 32768 per (b,h)

typedef __attribute__((ext_vector_type(8))) short bf16x8;
typedef __attribute__((ext_vector_type(4))) float f32x4;

#define MFMA32(A,B,C) __builtin_amdgcn_mfma_f32_16x16x32_bf16(A,B,C,0,0,0)

// workspace layout (f32 units)
#define WS_GAM   16ull
#define WS_AQOLD 256ull
#define WS_BKOLD (256ull + 65536ull)
#define WS_BUFS  131584ull
#define ARRE     4194304ull            // elems per bf16 array
#define WS_SUMS  (WS_BUFS + 12ull*2097152ull)
#define WS_AQM   WS_SUMS
#define WS_AQC   (WS_SUMS +  65536ull)
#define WS_BKM   (WS_SUMS + 131072ull)
#define WS_BKC   (WS_SUMS + 196608ull)
#define WS_AQF   (WS_SUMS + 262144ull)
#define WS_BKF   (WS_SUMS + 327680ull)
// bf16 array ids
#define A_QMH 0
#define A_QML 1
#define A_SCH 2
#define A_SCL 3
#define A_KMH 4
#define A_KML 5
#define A_SKH 6
#define A_SKL 7
#define A_VMT 8
#define A_VCT 9
#define A_OMH 10
#define A_OCH 11

__device__ __forceinline__ unsigned short* warr(float* wsf, int idx) {
  return (unsigned short*)(wsf + WS_BUFS) + (size_t)idx * ARRE;
}

// ---------- helpers ----------
__device__ __forceinline__ float bf2f(unsigned short h) {
  union { float f; unsigned u; } v; v.u = ((unsigned)h) << 16; return v.f;
}
__device__ __forceinline__ unsigned short f2bf(float f) {
  union { float f; unsigned u; } v; v.f = f;
  unsigned u = v.u;
  u += 0x7FFFu + ((u >> 16) & 1u);   // RNE
  return (unsigned short)(u >> 16);
}
__device__ __forceinline__ void ld8_bf16(const unsigned short* p, float* v) {
  uint4 r = *(const uint4*)p;
  v[0]=bf2f((unsigned short)(r.x&0xFFFFu)); v[1]=bf2f((unsigned short)(r.x>>16));
  v[2]=bf2f((unsigned short)(r.y&0xFFFFu)); v[3]=bf2f((unsigned short)(r.y>>16));
  v[4]=bf2f((unsigned short)(r.z&0xFFFFu)); v[5]=bf2f((unsigned short)(r.z>>16));
  v[6]=bf2f((unsigned short)(r.w&0xFFFFu)); v[7]=bf2f((unsigned short)(r.w>>16));
}
__device__ __forceinline__ void ld8_f32(const float* p, float* v) {
  float4 a = *(const float4*)p; float4 b = *(const float4*)(p+4);
  v[0]=a.x;v[1]=a.y;v[2]=a.z;v[3]=a.w;v[4]=b.x;v[5]=b.y;v[6]=b.z;v[7]=b.w;
}

// ---------- dtype probe ----------
__global__ void k_detect(const void* __restrict__ in0, int* __restrict__ flag) {
  __shared__ int cnt;
  if (threadIdx.x == 0) cnt = 0;
  __syncthreads();
  const unsigned short* p = (const unsigned short*)in0;
  unsigned short h = p[threadIdx.x * 2u];
  int e = (h >> 7) & 0xFF;
  if (e >= 97 && e <= 137) atomicAdd(&cnt, 1);
  __syncthreads();
  if (threadIdx.x == 0) *flag = (cnt >= 160) ? 1 : 0;
}

__global__ void k_gamma(const void* __restrict__ g_in, const int* __restrict__ flag,
                        float* __restrict__ gam) {
  int t = threadIdx.x;
  if (t >= NHEAD) return;
  float g = (*flag) ? bf2f(((const unsigned short*)g_in)[t]) : ((const float*)g_in)[t];
  float sp = (g > 20.f) ? g : log1pf(expf(g));
  gam[t] = -sp;
}

// ================= NEW bf16 MFMA path =================

// GEMM core: C[128x128] = X[128xK] * W^T (W row-major [n][k]), both bf16, K=512
__device__ __forceinline__ void gemm_core(const unsigned short* __restrict__ Xrow0,
                                          const unsigned short* __restrict__ Wrow0,
                                          unsigned short* As, unsigned short* Bs,
                                          int tid, f32x4 acc[4][4]) {
  const int l  = tid & 63;
  const int li = l & 15, lg = l >> 4;
  const int w = tid >> 6, wr = w >> 1, wc = w & 1;
  const int r0 = tid >> 2, c0 = tid & 3;
  const int r1 = r0 + 64;
  const int wo0 = r0*64 + ((c0 ^ ((r0>>1)&3))*16);
  const int wo1 = r1*64 + ((c0 ^ ((r1>>1)&3))*16);
  int roA[4], roB[4];
#pragma unroll
  for (int mi = 0; mi < 4; ++mi) {
    int r  = wr*64 + mi*16 + li;
    roA[mi] = r*64 + ((lg ^ ((r>>1)&3))*16);
    int rn = wc*64 + mi*16 + li;
    roB[mi] = rn*64 + ((lg ^ ((rn>>1)&3))*16);
  }
  const unsigned short* xp0 = Xrow0 + (size_t)r0*DMODEL + c0*8;
  const unsigned short* xp1 = Xrow0 + (size_t)r1*DMODEL + c0*8;
  const unsigned short* wp0 = Wrow0 + (size_t)r0*DMODEL + c0*8;
  const unsigned short* wp1 = Wrow0 + (size_t)r1*DMODEL + c0*8;
  uint4 ra0 = *(const uint4*)xp0;
  uint4 ra1 = *(const uint4*)xp1;
  uint4 rb0 = *(const uint4*)wp0;
  uint4 rb1 = *(const uint4*)wp1;
  for (int kt = 0; kt < DMODEL; kt += 32) {
    __syncthreads();
    *(uint4*)((char*)As + wo0) = ra0;
    *(uint4*)((char*)As + wo1) = ra1;
    *(uint4*)((char*)Bs + wo0) = rb0;
    *(uint4*)((char*)Bs + wo1) = rb1;
    __syncthreads();
    if (kt + 32 < DMODEL) {
      ra0 = *(const uint4*)(xp0 + kt + 32);
      ra1 = *(const uint4*)(xp1 + kt + 32);
      rb0 = *(const uint4*)(wp0 + kt + 32);
      rb1 = *(const uint4*)(wp1 + kt + 32);
    }
    bf16x8 af[4], bfv[4];
#pragma unroll
    for (int mi = 0; mi < 4; ++mi) {
      af[mi]  = *(const bf16x8*)((const char*)As + roA[mi]);
      bfv[mi] = *(const bf16x8*)((const char*)Bs + roB[mi]);
    }
#pragma unroll
    for (int mi = 0; mi < 4; ++mi)
#pragma unroll
      for (int nj = 0; nj < 4; ++nj)
        acc[mi][nj] = MFMA32(af[mi], bfv[nj], acc[mi][nj]);
  }
}

// projections: y = 0 qm, 1 km, 2 qc, 3 kc, 4 vm, 5 vc
__global__ __launch_bounds__(256) void k_projM(
    const void* xqm, const void* xkm, const void* xqc, const void* xkc,
    const void* xvm, const void* xvc,
    const void* wqm, const void* wkm, const void* wqc, const void* wkc,
    const void* wvm, const void* wvc,
    float* wsf, const int* __restrict__ flag)
{
  if (*flag != 1) return;
  __shared__ __align__(16) unsigned short As[4096];
  __shared__ __align__(16) unsigned short Bs[4096];
  const int y = blockIdx.y;
  const unsigned short* X;
  const unsigned short* W;
  unsigned short *outh = nullptr, *outl = nullptr;
  float* sums = nullptr;
  float qscale = 1.0f; int mode = 0;  // 0 mean, 1 cov, 2 v
  switch (y) {
    case 0: X=(const unsigned short*)xqm; W=(const unsigned short*)wqm;
            outh=warr(wsf,A_QMH); outl=warr(wsf,A_QML); sums=wsf+WS_AQM; qscale=0.25f; mode=0; break;
    case 1: X=(const unsigned short*)xkm; W=(const unsigned short*)wkm;
            outh=warr(wsf,A_KMH); outl=warr(wsf,A_KML); sums=wsf+WS_BKM; qscale=1.0f;  mode=0; break;
    case 2: X=(const unsigned short*)xqc; W=(const unsigned short*)wqc;
            outh=warr(wsf,A_SCH); outl=warr(wsf,A_SCL); sums=wsf+WS_AQC; qscale=0.25f; mode=1; break;
    case 3: X=(const unsigned short*)xkc; W=(const unsigned short*)wkc;
            outh=warr(wsf,A_SKH); outl=warr(wsf,A_SKL); sums=wsf+WS_BKC; qscale=1.0f;  mode=1; break;
    case 4: X=(const unsigned short*)xvm; W=(const unsigned short*)wvm;
            outh=warr(wsf,A_VMT); mode=2; break;
    default:X=(const unsigned short*)xvc; W=(const unsigned short*)wvc;
            outh=warr(wsf,A_VCT); mode=2; break;
  }
  const int tid = threadIdx.x;
  const int l = tid & 63, li = l & 15, lg = l >> 4;
  const int w = tid >> 6, wr = w >> 1, wc = w & 1;
  const int m0 = (blockIdx.x >> 2) * 128;
  const int n0 = (blockIdx.x & 3) * 128;
  f32x4 acc[4][4];
  f32x4 z = {0.f,0.f,0.f,0.f};
#pragma unroll
  for (int a = 0; a < 4; ++a)
#pragma unroll
    for (int b = 0; b < 4; ++b) acc[a][b] = z;

  gemm_core(X + (size_t)m0*DMODEL, W + (size_t)n0*DMODEL, As, Bs, tid, acc);

  const int head = ((n0 >> 6) + wc);
  if (mode <= 1) {
    // row sums (raw acc): mean -> sum sq, cov -> raw sum
#pragma unroll
    for (int mi = 0; mi < 4; ++mi)
#pragma unroll
      for (int reg = 0; reg < 4; ++reg) {
        float rs = 0.f;
#pragma unroll
        for (int nj = 0; nj < 4; ++nj) {
          float v = acc[mi][nj][reg];
          rs += (mode == 0) ? v*v : v;
        }
        rs += __shfl_xor(rs, 1); rs += __shfl_xor(rs, 2);
        rs += __shfl_xor(rs, 4); rs += __shfl_xor(rs, 8);
        if (li == 0) {
          int m = m0 + wr*64 + mi*16 + 4*lg + reg;
          sums[((size_t)(m >> 9)*NHEAD + head)*SEQ + (m & 511)] = rs;
        }
      }
    // hi/lo writes
#pragma unroll
    for (int mi = 0; mi < 4; ++mi)
#pragma unroll
      for (int nj = 0; nj < 4; ++nj)
#pragma unroll
        for (int reg = 0; reg < 4; ++reg) {
          float v = acc[mi][nj][reg];
          if (mode == 1) v = sqrtf(fmaxf(v, 1e-24f));
          v *= qscale;
          unsigned short h16 = f2bf(v);
          unsigned short l16 = f2bf(v - bf2f(h16));
          int m = m0 + wr*64 + mi*16 + 4*lg + reg;
          int n = n0 + wc*64 + nj*16 + li;
          size_t dst = ((size_t)((m >> 9)*NHEAD + (n >> 6))*SEQ + (m & 511))*DK + (n & 63);
          outh[dst] = h16; outl[dst] = l16;
        }
  } else {
    // V: write transposed [bh][d][s], pack 4 consecutive s per store
#pragma unroll
    for (int mi = 0; mi < 4; ++mi)
#pragma unroll
      for (int nj = 0; nj < 4; ++nj) {
        int mb = m0 + wr*64 + mi*16 + 4*lg;
        int n = n0 + wc*64 + nj*16 + li;
        int b = mb >> 9, s = mb & 511, d = n & 63;
        unsigned e0 = f2bf(acc[mi][nj][0]);
        unsigned e1 = f2bf(acc[mi][nj][1]);
        unsigned e2 = f2bf(acc[mi][nj][2]);
        unsigned e3 = f2bf(acc[mi][nj][3]);
        uint2 pk; pk.x = e0 | (e1 << 16); pk.y = e2 | (e3 << 16);
        *(uint2*)(outh + ((size_t)(b*NHEAD + head)*DK + d)*SEQ + s) = pk;
      }
  }
}

__global__ void k_sumAB(float* wsf, const int* __restrict__ flag) {
  if (*flag != 1) return;
  int i = blockIdx.x * 256 + threadIdx.x;
  if (i < NBH*SEQ) {
    (wsf+WS_AQF)[i] = 0.125f * ((wsf+WS_AQM)[i] + (wsf+WS_AQC)[i]);
    (wsf+WS_BKF)[i] = 0.125f * ((wsf+WS_BKM)[i] + (wsf+WS_BKC)[i]);
  }
}

// flash-style fused attention, 4 waves, wave = 16 query rows, QBLK=64
__global__ __launch_bounds__(256) void k_attn2(float* wsf, const int* __restrict__ flag)
{
  if (*flag != 1) return;
  __shared__ float s_bk[SEQ];
  __shared__ __align__(16) float s_out[4][2][16][68];

  const unsigned short* qmh = warr(wsf, A_QMH);
  const unsigned short* qml = warr(wsf, A_QML);
  const unsigned short* sch = warr(wsf, A_SCH);
  const unsigned short* scl = warr(wsf, A_SCL);
  const unsigned short* kmh = warr(wsf, A_KMH);
  const unsigned short* kml = warr(wsf, A_KML);
  const unsigned short* skh = warr(wsf, A_SKH);
  const unsigned short* skl = warr(wsf, A_SKL);
  const unsigned short* vmT = warr(wsf, A_VMT);
  const unsigned short* vcT = warr(wsf, A_VCT);
  unsigned short* omh = warr(wsf, A_OMH);
  unsigned short* och = warr(wsf, A_OCH);
  const float* AqF = wsf + WS_AQF;
  const float* BkF = wsf + WS_BKF;

  const int tid = threadIdx.x;
  const int l = tid & 63, li = l & 15, lg = l >> 4;
  const int w = tid >> 6;
  const int bh = blockIdx.x >> 3;
  const int qt = blockIdx.x & 7;
  const int i_base = qt*64 + w*16;
  const int i = i_base + li;
  const float gam = (wsf + WS_GAM)[bh & (NHEAD-1)];
  const float aq = AqF[(size_t)bh*SEQ + i];

  for (int idx = tid; idx < SEQ; idx += 256) s_bk[idx] = BkF[(size_t)bh*SEQ + idx];
  __syncthreads();

  // Q fragments (B-operand): [part][ks][hi/lo]
  bf16x8 qf[8];
  {
    const unsigned short* qb[4] = {qmh, qml, sch, scl};
#pragma unroll
    for (int part = 0; part < 2; ++part)
#pragma unroll
      for (int hl = 0; hl < 2; ++hl)
#pragma unroll
        for (int ks = 0; ks < 2; ++ks)
          qf[part*4 + ks*2 + hl] =
            *(const bf16x8*)(qb[part*2+hl] + ((size_t)bh*SEQ + i)*DK + ks*32 + lg*8);
  }
  const int ntile = (i_base >> 4) + 1;

  auto score_tile = [&](int t, float* s) {
    const int j0 = t*16;
    f32x4 acc = {0.f,0.f,0.f,0.f};
    const size_t krow = ((size_t)bh*SEQ + j0 + li)*DK + lg*8;
#pragma unroll
    for (int part = 0; part < 2; ++part) {
      const unsigned short* khp = part ? skh : kmh;
      const unsigned short* klp = part ? skl : kml;
#pragma unroll
      for (int ks = 0; ks < 2; ++ks) {
        bf16x8 kh = *(const bf16x8*)(khp + krow + ks*32);
        bf16x8 kl = *(const bf16x8*)(klp + krow + ks*32);
        acc = MFMA32(kh, qf[part*4+ks*2+0], acc);
        acc = MFMA32(kl, qf[part*4+ks*2+0], acc);
        acc = MFMA32(kh, qf[part*4+ks*2+1], acc);
      }
    }
    const float4 bk4 = *(const float4*)&s_bk[j0 + lg*4];
    float bks[4] = {bk4.x, bk4.y, bk4.z, bk4.w};
#pragma unroll
    for (int r = 0; r < 4; ++r) {
      int j = j0 + lg*4 + r;
      float v = acc[r] - aq - bks[r];
      s[r] = (j > i) ? -3.0e38f : v;
    }
  };

  // ---- pass 1: softmax-1 stats ----
  float m1 = -3.0e38f, tot = 0.f;
  for (int t = 0; t < ntile; ++t) {
    float s[4]; score_tile(t, s);
    float tm = fmaxf(fmaxf(s[0], s[1]), fmaxf(s[2], s[3]));
    tm = fmaxf(tm, __shfl_xor(tm, 16));
    tm = fmaxf(tm, __shfl_xor(tm, 32));
    float m1n = fmaxf(m1, tm);
    float lsum = __expf(s[0]-m1n) + __expf(s[1]-m1n) + __expf(s[2]-m1n) + __expf(s[3]-m1n);
    lsum += __shfl_xor(lsum, 16); lsum += __shfl_xor(lsum, 32);
    tot = tot * __expf(m1 - m1n) + lsum;
    m1 = m1n;
  }
  const float invtot = 1.0f / tot;

  // ---- pass 2: scan + online softmax-2 + PV ----
  f32x4 accm[4], accc[4];
  {
    f32x4 z = {0.f,0.f,0.f,0.f};
#pragma unroll
    for (int dt = 0; dt < 4; ++dt) { accm[dt] = z; accc[dt] = z; }
  }
  float run = 0.f, m2 = -3.0e38f, sum2 = 0.f;

  auto scan_tile = [&](int t, float* s2) {
    float s[4]; score_tile(t, s);
    float e0 = __expf(s[0]-m1), e1 = __expf(s[1]-m1),
          e2 = __expf(s[2]-m1), e3 = __expf(s[3]-m1);
    float p0 = e0, p1 = p0+e1, p2 = p1+e2, p3 = p2+e3;
    float lt = p3;
    float a = __shfl_up(lt, 16), b = __shfl_up(lt, 32), c = __shfl_up(lt, 48);
    float excl = (lg >= 1 ? a : 0.f) + (lg >= 2 ? b : 0.f) + (lg >= 3 ? c : 0.f);
    float base = run + excl;
    float cums[4] = {base+p0, base+p1, base+p2, base+p3};
    float ttr = lt;
    ttr += __shfl_xor(ttr, 16); ttr += __shfl_xor(ttr, 32);
    run += ttr;
#pragma unroll
    for (int r = 0; r < 4; ++r) {
      int j = t*16 + lg*4 + r;
      float rem = fmaxf(tot - cums[r], 0.f) * invtot;
      float pos = fmaxf((float)(i - j), 0.f);
      float dist = sqrtf(rem * pos);
      float eff = fmaxf(__expf(dist * gam), 1e-5f);
      s2[r] = (j > i) ? -3.0e38f : s[r] * eff;
    }
  };

  for (int t0 = 0; t0 < ntile; t0 += 2) {
    float s2A[4], s2B[4];
    scan_tile(t0, s2A);
    const bool hasB = (t0 + 1) < ntile;
    if (hasB) scan_tile(t0+1, s2B);
    else { s2B[0]=s2B[1]=s2B[2]=s2B[3] = -3.0e38f; }
    float mt = fmaxf(fmaxf(fmaxf(s2A[0],s2A[1]), fmaxf(s2A[2],s2A[3])),
                     fmaxf(fmaxf(s2B[0],s2B[1]), fmaxf(s2B[2],s2B[3])));
    mt = fmaxf(mt, __shfl_xor(mt, 16));
    mt = fmaxf(mt, __shfl_xor(mt, 32));
    float m2n = fmaxf(m2, mt);
    float scale = __expf(m2 - m2n);
    float scale2 = scale * scale;
#pragma unroll
    for (int dt = 0; dt < 4; ++dt) { accm[dt] *= scale; accc[dt] *= scale2; }
    float pA[4], pB[4];
#pragma unroll
    for (int r = 0; r < 4; ++r) { pA[r] = __expf(s2A[r]-m2n); pB[r] = __expf(s2B[r]-m2n); }
    float ps = pA[0]+pA[1]+pA[2]+pA[3] + pB[0]+pB[1]+pB[2]+pB[3];
    ps += __shfl_xor(ps, 16); ps += __shfl_xor(ps, 32);
    sum2 = sum2 * scale + ps;
    m2 = m2n;
    bf16x8 pbm, pbc;
#pragma unroll
    for (int r = 0; r < 4; ++r) {
      pbm[r]   = (short)f2bf(pA[r]);
      pbm[4+r] = (short)f2bf(pB[r]);
      pbc[r]   = (short)f2bf(pA[r]*pA[r]);
      pbc[4+r] = (short)f2bf(pB[r]*pB[r]);
    }
    const int j0A = t0*16;
    const int j0B = hasB ? j0A + 16 : j0A;
    union V16 { struct { uint2 lo, hi; } u; bf16x8 v; };
#pragma unroll
    for (int dt = 0; dt < 4; ++dt) {
      const size_t vrow = ((size_t)bh*DK + dt*16 + li)*SEQ;
      V16 vm_, vc_;
      vm_.u.lo = *(const uint2*)(vmT + vrow + j0A + lg*4);
      vm_.u.hi = *(const uint2*)(vmT + vrow + j0B + lg*4);
      vc_.u.lo = *(const uint2*)(vcT + vrow + j0A + lg*4);
      vc_.u.hi = *(const uint2*)(vcT + vrow + j0B + lg*4);
      accm[dt] = MFMA32(vm_.v, pbm, accm[dt]);
      accc[dt] = MFMA32(vc_.v, pbc, accc[dt]);
    }
  }

  // ---- finalize ----
  const float inv2 = 1.0f / sum2;
  const float inv2c = inv2 * inv2;
#pragma unroll
  for (int dt = 0; dt < 4; ++dt)
#pragma unroll
    for (int reg = 0; reg < 4; ++reg) {
      s_out[w][0][li][dt*16 + lg*4 + reg] = accm[dt][reg] * inv2;
      s_out[w][1][li][dt*16 + lg*4 + reg] = accc[dt][reg] * inv2c;
    }
  __syncthreads();
  const int row = l >> 2;
  const int dc = (l & 3) * 16;
  const int gi = i_base + row;
  const bool zero = (gi == 0);
  unsigned short* dsts[2] = {omh, och};
#pragma unroll
  for (int tn = 0; tn < 2; ++tn) {
    unsigned short* dst = dsts[tn] + ((size_t)bh*SEQ + gi)*DK + dc;
#pragma unroll
    for (int part = 0; part < 4; ++part) {
      float4 v4 = *(const float4*)&s_out[w][tn][row][dc + part*4];
      if (zero) { v4.x = 0.f; v4.y = 0.f; v4.z = 0.f; v4.w = 0.f; }
      uint2 pk;
      pk.x = (unsigned)f2bf(v4.x) | ((unsigned)f2bf(v4.y) << 16);
      pk.y = (unsigned)f2bf(v4.z) | ((unsigned)f2bf(v4.w) << 16);
      *(uint2*)(dst + part*4) = pk;
    }
  }
}

// output GEMM: d_out[m][n] = sum_k OM[bh(s),k] * Wo[n][k], bf16 MFMA
__global__ __launch_bounds__(256) void k_outM(float* wsf,
                                              const void* w_mean, const void* w_cov,
                                              void* outv, const int* __restrict__ flag)
{
  if (*flag != 1) return;
  __shared__ __align__(16) unsigned short As[4096];
  __shared__ __align__(16) unsigned short Bs[4096];
  const int y = blockIdx.y;
  const unsigned short* A = warr(wsf, y ? A_OCH : A_OMH);
  const unsigned short* W = (const unsigned short*)(y ? w_cov : w_mean);
  unsigned short* out = (unsigned short*)outv + (size_t)y * 4194304ull;

  const int tid = threadIdx.x;
  const int l = tid & 63, li = l & 15, lg = l >> 4;
  const int w = tid >> 6, wr = w >> 1, wc = w & 1;
  const int m0 = (blockIdx.x >> 2) * 128;
  const int n0 = (blockIdx.x & 3) * 128;
  const int r0 = tid >> 2, c0 = tid & 3;
  const int r1 = r0 + 64;
  const int wo0 = r0*64 + ((c0 ^ ((r0>>1)&3))*16);
  const int wo1 = r1*64 + ((c0 ^ ((r1>>1)&3))*16);
  int roA[4], roB[4];
#pragma unroll
  for (int mi = 0; mi < 4; ++mi) {
    int r  = wr*64 + mi*16 + li;
    roA[mi] = r*64 + ((lg ^ ((r>>1)&3))*16);
    int rn = wc*64 + mi*16 + li;
    roB[mi] = rn*64 + ((lg ^ ((rn>>1)&3))*16);
  }
  // A gather bases (b,s fixed per thread/chunk)
  const int mA0 = m0 + r0, mA1 = m0 + r1;
  const size_t abase0 = ((size_t)(mA0 >> 9) * NHEAD * SEQ + (mA0 & 511)) * DK;
  const size_t abase1 = ((size_t)(mA1 >> 9) * NHEAD * SEQ + (mA1 & 511)) * DK;
  const unsigned short* wp0 = W + (size_t)(n0 + r0)*DMODEL + c0*8;
  const unsigned short* wp1 = W + (size_t)(n0 + r1)*DMODEL + c0*8;

  f32x4 acc[4][4];
  f32x4 z = {0.f,0.f,0.f,0.f};
#pragma unroll
  for (int a = 0; a < 4; ++a)
#pragma unroll
    for (int b = 0; b < 4; ++b) acc[a][b] = z;

  auto aidx = [&](size_t abase, int k) -> const uint4* {
    return (const uint4*)(A + abase + (size_t)(k >> 6) * (SEQ*DK) + (k & 63));
  };
  int k0 = c0*8;
  uint4 ra0 = *aidx(abase0, k0);
  uint4 ra1 = *aidx(abase1, k0);
  uint4 rb0 = *(const uint4*)wp0;
  uint4 rb1 = *(const uint4*)wp1;
  for (int kt = 0; kt < DMODEL; kt += 32) {
    __syncthreads();
    *(uint4*)((char*)As + wo0) = ra0;
    *(uint4*)((char*)As + wo1) = ra1;
    *(uint4*)((char*)Bs + wo0) = rb0;
    *(uint4*)((char*)Bs + wo1) = rb1;
    __syncthreads();
    if (kt + 32 < DMODEL) {
      int kn = kt + 32 + c0*8;
      ra0 = *aidx(abase0, kn);
      ra1 = *aidx(abase1, kn);
      rb0 = *(const uint4*)(wp0 + kt + 32);
      rb1 = *(const uint4*)(wp1 + kt + 32);
    }
    bf16x8 af[4], bfv[4];
#pragma unroll
    for (int mi = 0; mi < 4; ++mi) {
      af[mi]  = *(const bf16x8*)((const char*)As + roA[mi]);
      bfv[mi] = *(const bf16x8*)((const char*)Bs + roB[mi]);
    }
#pragma unroll
    for (int mi = 0; mi < 4; ++mi)
#pragma unroll
      for (int nj = 0; nj < 4; ++nj)
        acc[mi][nj] = MFMA32(af[mi], bfv[nj], acc[mi][nj]);
  }
#pragma unroll
  for (int mi = 0; mi < 4; ++mi)
#pragma unroll
    for (int nj = 0; nj < 4; ++nj)
#pragma unroll
      for (int reg = 0; reg < 4; ++reg) {
        int m = m0 + wr*64 + mi*16 + 4*lg + reg;
        int n = n0 + wc*64 + nj*16 + li;
        out[(size_t)m*DMODEL + n] = f2bf(acc[mi][nj][reg]);
      }
}

// ================= OLD fp32 fallback path (flag==0) =================

template<int ISBF>
__global__ __launch_bounds__(256) void k_proj(const void* __restrict__ Xv,
                                              const void* __restrict__ Wv,
                                              const int* __restrict__ flag,
                                              float* __restrict__ out) {
  if (*flag != ISBF) return;
  __shared__ float As[16][132];
  __shared__ float Bs[16][132];
  const int tid = threadIdx.x;
  const int m0 = (blockIdx.x >> 2) * 128;
  const int n0 = (blockIdx.x & 3) * 128;
  const int lr = tid >> 1;
  const int lk = (tid & 1) * 8;
  const int tm = (tid >> 4) * 8;
  const int tn = (tid & 15) * 8;
  float acc[8][8];
#pragma unroll
  for (int i = 0; i < 8; ++i)
#pragma unroll
    for (int j = 0; j < 8; ++j) acc[i][j] = 0.f;

  for (int kt = 0; kt < DMODEL; kt += 16) {
    float xv[8], wv[8];
    if (ISBF) {
      ld8_bf16((const unsigned short*)Xv + (size_t)(m0+lr)*DMODEL + kt + lk, xv);
      ld8_bf16((const unsigned short*)Wv + (size_t)(n0+lr)*DMODEL + kt + lk, wv);
    } else {
      ld8_f32((const float*)Xv + (size_t)(m0+lr)*DMODEL + kt + lk, xv);
      ld8_f32((const float*)Wv + (size_t)(n0+lr)*DMODEL + kt + lk, wv);
    }
    __syncthreads();
#pragma unroll
    for (int i = 0; i < 8; ++i) { As[lk+i][lr] = xv[i]; Bs[lk+i][lr] = wv[i]; }
    __syncthreads();
#pragma unroll
    for (int k = 0; k < 16; ++k) {
      float a[8], b[8];
      *(float4*)&a[0] = *(const float4*)&As[k][tm];
      *(float4*)&a[4] = *(const float4*)&As[k][tm+4];
      *(float4*)&b[0] = *(const float4*)&Bs[k][tn];
      *(float4*)&b[4] = *(const float4*)&Bs[k][tn+4];
#pragma unroll
      for (int i = 0; i < 8; ++i)
#pragma unroll
        for (int j = 0; j < 8; ++j) acc[i][j] += a[i]*b[j];
    }
    __syncthreads();
  }
  const int nb = n0 + tn;
  const int hh = nb >> 6, d0 = nb & 63;
#pragma unroll
  for (int i = 0; i < 8; ++i) {
    int m = m0 + tm + i;
    int b = m >> 9, s = m & 511;
    float* dst = out + ((size_t)(b*NHEAD + hh)*SEQ + s)*DK + d0;
    *(float4*)dst       = make_float4(acc[i][0],acc[i][1],acc[i][2],acc[i][3]);
    *(float4*)(dst + 4) = make_float4(acc[i][4],acc[i][5],acc[i][6],acc[i][7]);
  }
}

__global__ __launch_bounds__(256) void k_rowsum(const float* __restrict__ a,
                                                float* __restrict__ c,
                                                float* __restrict__ outsum,
                                                const int* __restrict__ flag) {
  if (*flag != 0) return;
  const int row = blockIdx.x * 4 + (threadIdx.x >> 6);
  const int lane = threadIdx.x & 63;
  const size_t idx = (size_t)row * DK + lane;
  float av = a[idx];
  float cv = c[idx];
  float v = av*av + cv;
#pragma unroll
  for (int m = 32; m >= 1; m >>= 1) v += __shfl_xor(v, m, 64);
  if (lane == 0) outsum[row] = v;
  c[idx] = sqrtf(fmaxf(cv, 1e-24f));
}

__global__ __launch_bounds__(256) void k_attn(
    const float* __restrict__ qm, const float* __restrict__ sqc,
    const float* __restrict__ km, const float* __restrict__ skc,
    const float* __restrict__ vm, const float* __restrict__ vc,
    const float* __restrict__ Aq, const float* __restrict__ Bk,
    const float* __restrict__ gam_eff,
    float* __restrict__ om, float* __restrict__ oc,
    const int* __restrict__ flag)
{
  if (*flag != 0) return;
  __shared__ float s_s[16*528];
  __shared__ float s_kst[128*65];
  __shared__ float s_q[16*128];
  __shared__ float s_bk[SEQ];
  __shared__ float s_aq[16];
  __shared__ float s_inv2[16];

  const int tid  = threadIdx.x;
  const int tile = blockIdx.x & 31;
  const int bh   = blockIdx.x >> 5;
  const int hh   = bh & (NHEAD-1);
  const int i0   = tile * 16;
  const int imax = i0 + 15;
  const size_t hoff = (size_t)bh * HSZ;
  const float gam = gam_eff[hh];

  for (int idx = tid; idx < 2048; idx += 256) {
    int r = idx >> 7, d = idx & 127;
    size_t p = hoff + (size_t)(i0 + r) * DK;
    s_q[idx] = (d < 64) ? qm[p + d] : sqc[p + d - 64];
  }
  for (int idx = tid; idx < SEQ; idx += 256) s_bk[idx] = Bk[(size_t)bh*SEQ + idx];
  if (tid < 16) s_aq[tid] = Aq[(size_t)bh*SEQ + i0 + tid];
  __syncthreads();

  {
    const int rg = tid >> 6;
    const int jg = tid & 63;
    const int nchunk = (imax >> 7) + 1;
    for (int jc = 0; jc < nchunk; ++jc) {
      float acc[4][2];
#pragma unroll
      for (int rr = 0; rr < 4; ++rr) { acc[rr][0] = 0.f; acc[rr][1] = 0.f; }
#pragma unroll
      for (int part = 0; part < 2; ++part) {
        const float* kp = part ? skc : km;
        __syncthreads();
#pragma unroll
        for (int it = 0; it < 8; ++it) {
          int f4 = tid + it*256;
          int row = f4 >> 4, q4 = (f4 & 15) * 4;
          float4 v = *(const float4*)(kp + hoff + (size_t)(jc*128 + row)*DK + q4);
          float* dst = s_kst + row*65 + q4;
          dst[0]=v.x; dst[1]=v.y; dst[2]=v.z; dst[3]=v.w;
        }
        __syncthreads();
        const float* qb = s_q + part*64;
#pragma unroll 4
        for (int d = 0; d < 64; ++d) {
          float kv0 = s_kst[jg*65 + d];
          float kv1 = s_kst[(jg+64)*65 + d];
          float q0 = qb[(rg*4+0)*128 + d];
          float q1 = qb[(rg*4+1)*128 + d];
          float q2 = qb[(rg*4+2)*128 + d];
          float q3 = qb[(rg*4+3)*128 + d];
          acc[0][0] += q0*kv0; acc[0][1] += q0*kv1;
          acc[1][0] += q1*kv0; acc[1][1] += q1*kv1;
          acc[2][0] += q2*kv0; acc[2][1] += q2*kv1;
          acc[3][0] += q3*kv0; acc[3][1] += q3*kv1;
        }
      }
#pragma unroll
      for (int t = 0; t < 2; ++t) {
        int j = jc*128 + jg + 64*t;
        float bkj = s_bk[j];
#pragma unroll
        for (int rr = 0; rr < 4; ++rr) {
          int r = rg*4 + rr;
          float sc = (2.f*acc[rr][t] - s_aq[r] - bkj) * 0.125f;
          if (j > i0 + r) sc = -3.0e38f;
          s_s[r*528 + j + (j>>5)] = sc;
        }
      }
    }
  }
  __syncthreads();

  {
    const int r  = tid >> 4;
    const int jl = tid & 15;
    const int i  = i0 + r;
    const int jbase = jl * 32;
    int tmax = i + 1 - jbase; if (tmax > 32) tmax = 32; if (tmax < 0) tmax = 0;
    float* srow = s_s + r*528 + 33*jl;

    float m1 = -3.0e38f;
    for (int t = 0; t < tmax; ++t) m1 = fmaxf(m1, srow[t]);
#pragma unroll
    for (int mk = 1; mk < 16; mk <<= 1) m1 = fmaxf(m1, __shfl_xor(m1, mk, 16));

    float seg = 0.f;
    for (int t = 0; t < tmax; ++t) seg += expf(srow[t] - m1);
    float pref = seg;
#pragma unroll
    for (int off = 1; off < 16; off <<= 1) {
      float v = __shfl_up(pref, off, 16);
      if (jl >= off) pref += v;
    }
    float tot  = __shfl(pref, 15, 16);
    float excl = pref - seg;
    float inv1 = 1.0f / tot;

    float run = excl;
    float m2 = -3.0e38f;
    for (int t = 0; t < tmax; ++t) {
      int j = jbase + t;
      float sv = srow[t];
      float e = expf(sv - m1);
      run += e;
      float rem = fmaxf((tot - run) * inv1, 0.f);
      float dist = sqrtf(rem * (float)(i - j));
      float eff = fminf(fmaxf(expf(dist * gam), 1e-5f), 1e5f);
      float s2 = sv * eff;
      srow[t] = s2;
      m2 = fmaxf(m2, s2);
    }
#pragma unroll
    for (int mk = 1; mk < 16; mk <<= 1) m2 = fmaxf(m2, __shfl_xor(m2, mk, 16));

    float sum2 = 0.f;
    for (int t = 0; t < tmax; ++t) {
      float e2 = expf(srow[t] - m2);
      srow[t] = e2;
      sum2 += e2;
    }
#pragma unroll
    for (int mk = 1; mk < 16; mk <<= 1) sum2 += __shfl_xor(sum2, mk, 16);
    if (jl == 0) s_inv2[r] = 1.0f / sum2;
  }
  __syncthreads();

  {
    const int rg = tid >> 6;
    const int js = (tid >> 4) & 3;
    const int dq = (tid & 15) * 4;
    float am[4][4], ac[4][4];
#pragma unroll
    for (int rr = 0; rr < 4; ++rr)
#pragma unroll
      for (int dd = 0; dd < 4; ++dd) { am[rr][dd] = 0.f; ac[rr][dd] = 0.f; }

    const int jstart = js * 128;
    if (jstart <= imax) {
      float inv[4];
#pragma unroll
      for (int rr = 0; rr < 4; ++rr) inv[rr] = s_inv2[rg*4+rr];
      int jjmax = imax + 1 - jstart; if (jjmax > 128) jjmax = 128;
      for (int jj = 0; jj < jjmax; ++jj) {
        int j = jstart + jj;
        float4 vmv = *(const float4*)(vm + hoff + (size_t)j*DK + dq);
        float4 vcv = *(const float4*)(vc + hoff + (size_t)j*DK + dq);
#pragma unroll
        for (int rr = 0; rr < 4; ++rr) {
          int i = i0 + rg*4 + rr;
          float p2 = (j <= i) ? s_s[(rg*4+rr)*528 + j + (j>>5)] * inv[rr] : 0.f;
          float pc = p2 * p2;
          am[rr][0] += p2*vmv.x; am[rr][1] += p2*vmv.y;
          am[rr][2] += p2*vmv.z; am[rr][3] += p2*vmv.w;
          ac[rr][0] += pc*vcv.x; ac[rr][1] += pc*vcv.y;
          ac[rr][2] += pc*vcv.z; ac[rr][3] += pc*vcv.w;
        }
      }
    }
#pragma unroll
    for (int rr = 0; rr < 4; ++rr)
#pragma unroll
      for (int dd = 0; dd < 4; ++dd) {
        s_kst[((js*2+0)*16 + rg*4+rr)*64 + dq+dd] = am[rr][dd];
        s_kst[((js*2+1)*16 + rg*4+rr)*64 + dq+dd] = ac[rr][dd];
      }
    __syncthreads();
    for (int o = tid; o < 2048; o += 256) {
      int d = o & 63, r = (o >> 6) & 15, mc = o >> 10;
      float v = s_kst[((0+mc)*16 + r)*64 + d]
              + s_kst[((2+mc)*16 + r)*64 + d]
              + s_kst[((4+mc)*16 + r)*64 + d]
              + s_kst[((6+mc)*16 + r)*64 + d];
      if (i0 + r == 0) v = 0.f;
      float* dst = mc ? oc : om;
      dst[hoff + (size_t)(i0+r)*DK + d] = v;
    }
  }
}

template<int ISBF>
__global__ __launch_bounds__(256) void k_out(const float* __restrict__ Aws,
                                             const void* __restrict__ Wv,
                                             const int* __restrict__ flag,
                                             void* __restrict__ outv,
                                             size_t out_off) {
  if (*flag != ISBF) return;
  __shared__ float As[16][132];
  __shared__ float Bs[16][132];
  const int tid = threadIdx.x;
  const int m0 = (blockIdx.x >> 2) * 128;
  const int n0 = (blockIdx.x & 3) * 128;
  const int lr = tid >> 1;
  const int lk = (tid & 1) * 8;
  const int tm = (tid >> 4) * 8;
  const int tn = (tid & 15) * 8;
  float acc[8][8];
#pragma unroll
  for (int i = 0; i < 8; ++i)
#pragma unroll
    for (int j = 0; j < 8; ++j) acc[i][j] = 0.f;

  for (int kt = 0; kt < DMODEL; kt += 16) {
    int m = m0 + lr, k = kt + lk;
    const float* ap = Aws + ((size_t)((m >> 9)*NHEAD + (k >> 6))*SEQ + (m & 511))*DK + (k & 63);
    float xv[8], wv[8];
    ld8_f32(ap, xv);
    if (ISBF) ld8_bf16((const unsigned short*)Wv + (size_t)(n0+lr)*DMODEL + kt + lk, wv);
    else      ld8_f32((const float*)Wv + (size_t)(n0+lr)*DMODEL + kt + lk, wv);
    __syncthreads();
#pragma unroll
    for (int i = 0; i < 8; ++i) { As[lk+i][lr] = xv[i]; Bs[lk+i][lr] = wv[i]; }
    __syncthreads();
#pragma unroll
    for (int k2 = 0; k2 < 16; ++k2) {
      float a[8], b[8];
      *(float4*)&a[0] = *(const float4*)&As[k2][tm];
      *(float4*)&a[4] = *(const float4*)&As[k2][tm+4];
      *(float4*)&b[0] = *(const float4*)&Bs[k2][tn];
      *(float4*)&b[4] = *(const float4*)&Bs[k2][tn+4];
#pragma unroll
      for (int i = 0; i < 8; ++i)
#pragma unroll
        for (int j = 0; j < 8; ++j) acc[i][j] += a[i]*b[j];
    }
    __syncthreads();
  }
#pragma unroll
  for (int i = 0; i < 8; ++i) {
    int m = m0 + tm + i;
    size_t base = out_off + (size_t)m*DMODEL + n0 + tn;
    float* o = (float*)outv;
    *(float4*)(o + base)     = make_float4(acc[i][0],acc[i][1],acc[i][2],acc[i][3]);
    *(float4*)(o + base + 4) = make_float4(acc[i][4],acc[i][5],acc[i][6],acc[i][7]);
  }
}

extern "C" void kernel_launch(void* const* d_in, const int* in_sizes, int n_in,
                              void* d_out, int out_size, void* d_ws, size_t ws_size,
                              hipStream_t stream) {
  (void)in_sizes; (void)n_in; (void)out_size; (void)ws_size;
  float* wsf  = (float*)d_ws;
  int*   flag = (int*)d_ws;
  float* gam  = wsf + WS_GAM;
  float* Aqp  = wsf + WS_AQOLD;
  float* Bkp  = wsf + WS_BKOLD;
  float* bufs = wsf + WS_BUFS;
  const size_t SZ = (size_t)NBH * HSZ;
  float* qm  = bufs;
  float* sqc = bufs + 1*SZ;
  float* km  = bufs + 2*SZ;
  float* skc = bufs + 3*SZ;
  float* vm  = bufs + 4*SZ;
  float* vc  = bufs + 5*SZ;
  float* om  = bufs + 6*SZ;
  float* oc  = bufs + 7*SZ;

  k_detect<<<1, 256, 0, stream>>>(d_in[0], flag);
  k_gamma<<<1, 64, 0, stream>>>(d_in[14], flag, gam);

  // ---- new bf16 MFMA path (flag==1) ----
  k_projM<<<dim3(256, 6), 256, 0, stream>>>(
      d_in[0], d_in[2], d_in[1], d_in[3], d_in[4], d_in[5],
      d_in[6], d_in[8], d_in[7], d_in[9], d_in[10], d_in[11],
      wsf, flag);
  k_sumAB<<<256, 256, 0, stream>>>(wsf, flag);
  k_attn2<<<1024, 256, 0, stream>>>(wsf, flag);
  k_outM<<<dim3(256, 2), 256, 0, stream>>>(wsf, d_in[12], d_in[13], d_out, flag);

  // ---- old fp32 fallback path (flag==0) ----
  float* pouts[6] = {qm, sqc, km, skc, vm, vc};
  for (int p = 0; p < 6; ++p)
    k_proj<0><<<256, 256, 0, stream>>>(d_in[p], d_in[6+p], flag, pouts[p]);
  k_rowsum<<<16384, 256, 0, stream>>>(qm, sqc, Aqp, flag);
  k_rowsum<<<16384, 256, 0, stream>>>(km, skc, Bkp, flag);
  k_attn<<<4096, 256, 0, stream>>>(qm, sqc, km, skc, vm, vc, Aqp, Bkp, gam, om, oc, flag);
  k_out<0><<<256, 256, 0, stream>>>(om, d_in[12], flag, d_out, 0);
  k_out<0><<<256, 256, 0, stream>>>(oc, d_in[13], flag, d_out, (size_t)4194304);
}

// Round 6
// 508.823 us; speedup vs baseline: 2.5020x; 2.5020x over previous
//
#include <hip/hip_runtime.h>
#include <hip/hip_bf16.h>

#define SEQ    512
#define DMODEL 512
#define NHEAD  8
#define DK     64
#define BS     16
#define NBH    (BS*NHEAD)       // 128
#define HSZ    (SEQ*DK)         // 32768 per (b,h)

typedef __attribute__((ext_vector_type(8))) short bf16x8;
typedef __attribute__((ext_vector_type(4))) float f32x4;

#define MFMA32(A,B,C) __builtin_amdgcn_mfma_f32_16x16x32_bf16(A,B,C,0,0,0)

// ---------------- workspace layout (fp32 units) ----------------
#define WS_GAM 16ull
#define WS_AQM 256ull
#define WS_AQC (WS_AQM +  65536ull)
#define WS_BKM (WS_AQM + 131072ull)
#define WS_BKC (WS_AQM + 196608ull)
#define WS_AQF (WS_AQM + 262144ull)
#define WS_BKF (WS_AQM + 327680ull)
#define WS_OM  1048576ull
#define WS_OC  (WS_OM + 4194304ull)
#define WS_BF  (WS_OC + 4194304ull)     // bf16 arrays region
#define ARRE   4194304ull               // elems per bf16 array
// bf16 array ids
#define A_QMH 0
#define A_QML 1
#define A_SCH 2
#define A_SCL 3
#define A_KMH 4
#define A_KML 5
#define A_SKH 6
#define A_SKL 7
#define A_VMT 8
#define A_VCT 9

__device__ __forceinline__ unsigned short* warr(float* wsf, int idx) {
  return (unsigned short*)(wsf + WS_BF) + (size_t)idx * ARRE;
}

// ---------- helpers ----------
__device__ __forceinline__ float bf2f(unsigned short h) {
  union { float f; unsigned u; } v; v.u = ((unsigned)h) << 16; return v.f;
}
__device__ __forceinline__ unsigned short f2bf(float f) {
  union { float f; unsigned u; } v; v.f = f;
  unsigned u = v.u;
  u += 0x7FFFu + ((u >> 16) & 1u);   // RNE
  return (unsigned short)(u >> 16);
}
__device__ __forceinline__ void ld8_f32(const float* p, float* v) {
  float4 a = *(const float4*)p; float4 b = *(const float4*)(p+4);
  v[0]=a.x;v[1]=a.y;v[2]=a.z;v[3]=a.w;v[4]=b.x;v[5]=b.y;v[6]=b.z;v[7]=b.w;
}
// fp32[8] -> bf16 hi[8], lo[8] (packed uint4 each)
__device__ __forceinline__ void cvt8(const float* v, uint4& h, uint4& l) {
  unsigned hh[8], ll[8];
#pragma unroll
  for (int e = 0; e < 8; ++e) {
    unsigned short hb = f2bf(v[e]);
    hh[e] = hb;
    ll[e] = f2bf(v[e] - bf2f(hb));
  }
  h.x = hh[0]|(hh[1]<<16); h.y = hh[2]|(hh[3]<<16);
  h.z = hh[4]|(hh[5]<<16); h.w = hh[6]|(hh[7]<<16);
  l.x = ll[0]|(ll[1]<<16); l.y = ll[2]|(ll[3]<<16);
  l.z = ll[4]|(ll[5]<<16); l.w = ll[6]|(ll[7]<<16);
}

__global__ void k_gamma(const float* __restrict__ g_in, float* __restrict__ wsf) {
  int t = threadIdx.x;
  if (t >= NHEAD) return;
  float g = g_in[t];
  float sp = (g > 20.f) ? g : log1pf(expf(g));
  (wsf + WS_GAM)[t] = -sp;
}

// ---------------- projections (fp32 in, hi/lo bf16 3-term MFMA) ----------------
// y: 0 qm, 1 km, 2 qc, 3 kc, 4 vm, 5 vc
__global__ __launch_bounds__(256) void k_projM(
    const float* xqm, const float* xqc, const float* xkm, const float* xkc,
    const float* xvm, const float* xvc,
    const float* wqm, const float* wqc, const float* wkm, const float* wkc,
    const float* wvm, const float* wvc,
    float* wsf)
{
  __shared__ __align__(16) unsigned short Ah[4096];
  __shared__ __align__(16) unsigned short Al[4096];
  __shared__ __align__(16) unsigned short Bh[4096];
  __shared__ __align__(16) unsigned short Bl[4096];
  const int y = blockIdx.y;
  const float* X; const float* W;
  unsigned short *outh = nullptr, *outl = nullptr;
  float* sums = nullptr;
  float qscale = 1.0f; int mode = 0;  // 0 mean, 1 cov, 2 v
  switch (y) {
    case 0: X=xqm; W=wqm; outh=warr(wsf,A_QMH); outl=warr(wsf,A_QML); sums=wsf+WS_AQM; qscale=0.25f; mode=0; break;
    case 1: X=xkm; W=wkm; outh=warr(wsf,A_KMH); outl=warr(wsf,A_KML); sums=wsf+WS_BKM; qscale=1.0f;  mode=0; break;
    case 2: X=xqc; W=wqc; outh=warr(wsf,A_SCH); outl=warr(wsf,A_SCL); sums=wsf+WS_AQC; qscale=0.25f; mode=1; break;
    case 3: X=xkc; W=wkc; outh=warr(wsf,A_SKH); outl=warr(wsf,A_SKL); sums=wsf+WS_BKC; qscale=1.0f;  mode=1; break;
    case 4: X=xvm; W=wvm; outh=warr(wsf,A_VMT); mode=2; break;
    default:X=xvc; W=wvc; outh=warr(wsf,A_VCT); mode=2; break;
  }
  const int tid = threadIdx.x;
  const int l = tid & 63, li = l & 15, lg = l >> 4;
  const int w = tid >> 6, wr = w >> 1, wc = w & 1;
  const int m0 = (blockIdx.x >> 2) * 128;
  const int n0 = (blockIdx.x & 3) * 128;
  const int r0 = tid >> 2, c0 = tid & 3, r1 = r0 + 64;
  const int wo0 = r0*64 + ((c0 ^ ((r0>>1)&3))*16);
  const int wo1 = r1*64 + ((c0 ^ ((r1>>1)&3))*16);
  int roA[4], roB[4];
#pragma unroll
  for (int mi = 0; mi < 4; ++mi) {
    int r  = wr*64 + mi*16 + li;
    roA[mi] = r*64 + ((lg ^ ((r>>1)&3))*16);
    int rn = wc*64 + mi*16 + li;
    roB[mi] = rn*64 + ((lg ^ ((rn>>1)&3))*16);
  }
  const float* xp0 = X + (size_t)(m0+r0)*DMODEL + c0*8;
  const float* xp1 = X + (size_t)(m0+r1)*DMODEL + c0*8;
  const float* wp0 = W + (size_t)(n0+r0)*DMODEL + c0*8;
  const float* wp1 = W + (size_t)(n0+r1)*DMODEL + c0*8;
  uint4 a0h,a0l,a1h,a1l,b0h,b0l,b1h,b1l;
  {
    float t8[8];
    ld8_f32(xp0, t8); cvt8(t8, a0h, a0l);
    ld8_f32(xp1, t8); cvt8(t8, a1h, a1l);
    ld8_f32(wp0, t8); cvt8(t8, b0h, b0l);
    ld8_f32(wp1, t8); cvt8(t8, b1h, b1l);
  }
  f32x4 acc[4][4];
  f32x4 z = {0.f,0.f,0.f,0.f};
#pragma unroll
  for (int a = 0; a < 4; ++a)
#pragma unroll
    for (int b = 0; b < 4; ++b) acc[a][b] = z;

  for (int kt = 0; kt < DMODEL; kt += 32) {
    __syncthreads();
    *(uint4*)((char*)Ah + wo0) = a0h; *(uint4*)((char*)Al + wo0) = a0l;
    *(uint4*)((char*)Ah + wo1) = a1h; *(uint4*)((char*)Al + wo1) = a1l;
    *(uint4*)((char*)Bh + wo0) = b0h; *(uint4*)((char*)Bl + wo0) = b0l;
    *(uint4*)((char*)Bh + wo1) = b1h; *(uint4*)((char*)Bl + wo1) = b1l;
    __syncthreads();
    if (kt + 32 < DMODEL) {
      float t8[8];
      ld8_f32(xp0 + kt + 32, t8); cvt8(t8, a0h, a0l);
      ld8_f32(xp1 + kt + 32, t8); cvt8(t8, a1h, a1l);
      ld8_f32(wp0 + kt + 32, t8); cvt8(t8, b0h, b0l);
      ld8_f32(wp1 + kt + 32, t8); cvt8(t8, b1h, b1l);
    }
    bf16x8 ah[4], alo[4], bh[4], blo[4];
#pragma unroll
    for (int mi = 0; mi < 4; ++mi) {
      ah[mi]  = *(const bf16x8*)((const char*)Ah + roA[mi]);
      alo[mi] = *(const bf16x8*)((const char*)Al + roA[mi]);
      bh[mi]  = *(const bf16x8*)((const char*)Bh + roB[mi]);
      blo[mi] = *(const bf16x8*)((const char*)Bl + roB[mi]);
    }
#pragma unroll
    for (int mi = 0; mi < 4; ++mi)
#pragma unroll
      for (int nj = 0; nj < 4; ++nj) {
        acc[mi][nj] = MFMA32(ah[mi],  bh[nj],  acc[mi][nj]);
        acc[mi][nj] = MFMA32(alo[mi], bh[nj],  acc[mi][nj]);
        acc[mi][nj] = MFMA32(ah[mi],  blo[nj], acc[mi][nj]);
      }
  }

  const int head = ((n0 >> 6) + wc);
  if (mode <= 1) {
#pragma unroll
    for (int mi = 0; mi < 4; ++mi)
#pragma unroll
      for (int reg = 0; reg < 4; ++reg) {
        float rs = 0.f;
#pragma unroll
        for (int nj = 0; nj < 4; ++nj) {
          float v = acc[mi][nj][reg];
          rs += (mode == 0) ? v*v : v;
        }
        rs += __shfl_xor(rs, 1); rs += __shfl_xor(rs, 2);
        rs += __shfl_xor(rs, 4); rs += __shfl_xor(rs, 8);
        if (li == 0) {
          int m = m0 + wr*64 + mi*16 + 4*lg + reg;
          sums[((size_t)(m >> 9)*NHEAD + head)*SEQ + (m & 511)] = rs;
        }
      }
#pragma unroll
    for (int mi = 0; mi < 4; ++mi)
#pragma unroll
      for (int nj = 0; nj < 4; ++nj)
#pragma unroll
        for (int reg = 0; reg < 4; ++reg) {
          float v = acc[mi][nj][reg];
          if (mode == 1) v = sqrtf(fmaxf(v, 1e-24f));
          v *= qscale;
          unsigned short h16 = f2bf(v);
          unsigned short l16 = f2bf(v - bf2f(h16));
          int m = m0 + wr*64 + mi*16 + 4*lg + reg;
          int n = n0 + wc*64 + nj*16 + li;
          size_t dst = ((size_t)((m >> 9)*NHEAD + (n >> 6))*SEQ + (m & 511))*DK + (n & 63);
          outh[dst] = h16; outl[dst] = l16;
        }
  } else {
    // V: transposed [bh][d][s], 4 consecutive s per store
#pragma unroll
    for (int mi = 0; mi < 4; ++mi)
#pragma unroll
      for (int nj = 0; nj < 4; ++nj) {
        int mb = m0 + wr*64 + mi*16 + 4*lg;
        int n = n0 + wc*64 + nj*16 + li;
        int b = mb >> 9, s = mb & 511, d = n & 63;
        unsigned e0 = f2bf(acc[mi][nj][0]);
        unsigned e1 = f2bf(acc[mi][nj][1]);
        unsigned e2 = f2bf(acc[mi][nj][2]);
        unsigned e3 = f2bf(acc[mi][nj][3]);
        uint2 pk; pk.x = e0 | (e1 << 16); pk.y = e2 | (e3 << 16);
        *(uint2*)(outh + ((size_t)(b*NHEAD + head)*DK + d)*SEQ + s) = pk;
      }
  }
}

__global__ void k_sumAB(float* wsf) {
  int i = blockIdx.x * 256 + threadIdx.x;
  if (i < NBH*SEQ) {
    (wsf+WS_AQF)[i] = 0.125f * ((wsf+WS_AQM)[i] + (wsf+WS_AQC)[i]);
    (wsf+WS_BKF)[i] = 0.125f * ((wsf+WS_BKM)[i] + (wsf+WS_BKC)[i]);
  }
}

// ---------------- flash-style fused attention ----------------
__global__ __launch_bounds__(256) void k_attn2(float* wsf)
{
  __shared__ float s_bk[SEQ];
  __shared__ __align__(16) float s_out[4][2][16][68];

  const unsigned short* qmh = warr(wsf, A_QMH);
  const unsigned short* qml = warr(wsf, A_QML);
  const unsigned short* sch = warr(wsf, A_SCH);
  const unsigned short* scl = warr(wsf, A_SCL);
  const unsigned short* kmh = warr(wsf, A_KMH);
  const unsigned short* kml = warr(wsf, A_KML);
  const unsigned short* skh = warr(wsf, A_SKH);
  const unsigned short* skl = warr(wsf, A_SKL);
  const unsigned short* vmT = warr(wsf, A_VMT);
  const unsigned short* vcT = warr(wsf, A_VCT);
  float* omF = wsf + WS_OM;
  float* ocF = wsf + WS_OC;
  const float* AqF = wsf + WS_AQF;
  const float* BkF = wsf + WS_BKF;

  const int tid = threadIdx.x;
  const int l = tid & 63, li = l & 15, lg = l >> 4;
  const int w = tid >> 6;
  const int bh = blockIdx.x >> 3;
  const int qt = blockIdx.x & 7;
  const int i_base = qt*64 + w*16;
  const int i = i_base + li;
  const float gam = (wsf + WS_GAM)[bh & (NHEAD-1)];
  const float aq = AqF[(size_t)bh*SEQ + i];

  for (int idx = tid; idx < SEQ; idx += 256) s_bk[idx] = BkF[(size_t)bh*SEQ + idx];
  __syncthreads();

  // Q fragments (B-operand): [part][ks][hi/lo]
  bf16x8 qf[8];
  {
    const unsigned short* qb[4] = {qmh, qml, sch, scl};
#pragma unroll
    for (int part = 0; part < 2; ++part)
#pragma unroll
      for (int hl = 0; hl < 2; ++hl)
#pragma unroll
        for (int ks = 0; ks < 2; ++ks)
          qf[part*4 + ks*2 + hl] =
            *(const bf16x8*)(qb[part*2+hl] + ((size_t)bh*SEQ + i)*DK + ks*32 + lg*8);
  }
  const int ntile = (i_base >> 4) + 1;

  auto score_tile = [&](int t, float* s) {
    const int j0 = t*16;
    f32x4 accA = {0.f,0.f,0.f,0.f};   // hi*hi chain
    f32x4 accB = {0.f,0.f,0.f,0.f};   // correction chain
    const size_t krow = ((size_t)bh*SEQ + j0 + li)*DK + lg*8;
#pragma unroll
    for (int part = 0; part < 2; ++part) {
      const unsigned short* khp = part ? skh : kmh;
      const unsigned short* klp = part ? skl : kml;
#pragma unroll
      for (int ks = 0; ks < 2; ++ks) {
        bf16x8 kh = *(const bf16x8*)(khp + krow + ks*32);
        bf16x8 kl = *(const bf16x8*)(klp + krow + ks*32);
        accA = MFMA32(kh, qf[part*4+ks*2+0], accA);
        accB = MFMA32(kl, qf[part*4+ks*2+0], accB);
        accB = MFMA32(kh, qf[part*4+ks*2+1], accB);
      }
    }
    const float4 bk4 = *(const float4*)&s_bk[j0 + lg*4];
    float bks[4] = {bk4.x, bk4.y, bk4.z, bk4.w};
#pragma unroll
    for (int r = 0; r < 4; ++r) {
      int j = j0 + lg*4 + r;
      float v = (accA[r] + accB[r]) - aq - bks[r];
      s[r] = (j > i) ? -3.0e38f : v;
    }
  };

  // ---- pass 1: softmax-1 stats ----
  float m1 = -3.0e38f, tot = 0.f;
  for (int t = 0; t < ntile; ++t) {
    float s[4]; score_tile(t, s);
    float tm = fmaxf(fmaxf(s[0], s[1]), fmaxf(s[2], s[3]));
    tm = fmaxf(tm, __shfl_xor(tm, 16));
    tm = fmaxf(tm, __shfl_xor(tm, 32));
    float m1n = fmaxf(m1, tm);
    float lsum = __expf(s[0]-m1n) + __expf(s[1]-m1n) + __expf(s[2]-m1n) + __expf(s[3]-m1n);
    lsum += __shfl_xor(lsum, 16); lsum += __shfl_xor(lsum, 32);
    tot = tot * __expf(m1 - m1n) + lsum;
    m1 = m1n;
  }
  const float invtot = 1.0f / tot;

  // ---- pass 2: scan + online softmax-2 + PV ----
  f32x4 accm[4], accc[4];
  {
    f32x4 z = {0.f,0.f,0.f,0.f};
#pragma unroll
    for (int dt = 0; dt < 4; ++dt) { accm[dt] = z; accc[dt] = z; }
  }
  float run = 0.f, m2 = -3.0e38f, sum2 = 0.f;

  auto scan_tile = [&](int t, float* s2) {
    float s[4]; score_tile(t, s);
    float e0 = __expf(s[0]-m1), e1 = __expf(s[1]-m1),
          e2 = __expf(s[2]-m1), e3 = __expf(s[3]-m1);
    float p0 = e0, p1 = p0+e1, p2 = p1+e2, p3 = p2+e3;
    float lt = p3;
    float a = __shfl_up(lt, 16), b = __shfl_up(lt, 32), c = __shfl_up(lt, 48);
    float excl = (lg >= 1 ? a : 0.f) + (lg >= 2 ? b : 0.f) + (lg >= 3 ? c : 0.f);
    float base = run + excl;
    float cums[4] = {base+p0, base+p1, base+p2, base+p3};
    float ttr = lt;
    ttr += __shfl_xor(ttr, 16); ttr += __shfl_xor(ttr, 32);
    run += ttr;
#pragma unroll
    for (int r = 0; r < 4; ++r) {
      int j = t*16 + lg*4 + r;
      float rem = fmaxf(tot - cums[r], 0.f) * invtot;
      float pos = fmaxf((float)(i - j), 0.f);
      float dist = sqrtf(rem * pos);
      float eff = fmaxf(__expf(dist * gam), 1e-5f);
      s2[r] = (j > i) ? -3.0e38f : s[r] * eff;
    }
  };

  for (int t0 = 0; t0 < ntile; t0 += 2) {
    float s2A[4], s2B[4];
    scan_tile(t0, s2A);
    const bool hasB = (t0 + 1) < ntile;
    if (hasB) scan_tile(t0+1, s2B);
    else { s2B[0]=s2B[1]=s2B[2]=s2B[3] = -3.0e38f; }
    float mt = fmaxf(fmaxf(fmaxf(s2A[0],s2A[1]), fmaxf(s2A[2],s2A[3])),
                     fmaxf(fmaxf(s2B[0],s2B[1]), fmaxf(s2B[2],s2B[3])));
    mt = fmaxf(mt, __shfl_xor(mt, 16));
    mt = fmaxf(mt, __shfl_xor(mt, 32));
    float m2n = fmaxf(m2, mt);
    float scale = __expf(m2 - m2n);
    float scale2 = scale * scale;
#pragma unroll
    for (int dt = 0; dt < 4; ++dt) { accm[dt] *= scale; accc[dt] *= scale2; }
    float pA[4], pB[4];
#pragma unroll
    for (int r = 0; r < 4; ++r) { pA[r] = __expf(s2A[r]-m2n); pB[r] = __expf(s2B[r]-m2n); }
    float ps = pA[0]+pA[1]+pA[2]+pA[3] + pB[0]+pB[1]+pB[2]+pB[3];
    ps += __shfl_xor(ps, 16); ps += __shfl_xor(ps, 32);
    sum2 = sum2 * scale + ps;
    m2 = m2n;
    bf16x8 pbm, pbc;
#pragma unroll
    for (int r = 0; r < 4; ++r) {
      pbm[r]   = (short)f2bf(pA[r]);
      pbm[4+r] = (short)f2bf(pB[r]);
      pbc[r]   = (short)f2bf(pA[r]*pA[r]);
      pbc[4+r] = (short)f2bf(pB[r]*pB[r]);
    }
    const int j0A = t0*16;
    const int j0B = hasB ? j0A + 16 : j0A;
    union V16 { struct { uint2 lo, hi; } u; bf16x8 v; };
#pragma unroll
    for (int dt = 0; dt < 4; ++dt) {
      const size_t vrow = ((size_t)bh*DK + dt*16 + li)*SEQ;
      V16 vm_, vc_;
      vm_.u.lo = *(const uint2*)(vmT + vrow + j0A + lg*4);
      vm_.u.hi = *(const uint2*)(vmT + vrow + j0B + lg*4);
      vc_.u.lo = *(const uint2*)(vcT + vrow + j0A + lg*4);
      vc_.u.hi = *(const uint2*)(vcT + vrow + j0B + lg*4);
      accm[dt] = MFMA32(vm_.v, pbm, accm[dt]);
      accc[dt] = MFMA32(vc_.v, pbc, accc[dt]);
    }
  }

  // ---- finalize ----
  const float inv2 = 1.0f / sum2;
  const float inv2c = inv2 * inv2;
#pragma unroll
  for (int dt = 0; dt < 4; ++dt)
#pragma unroll
    for (int reg = 0; reg < 4; ++reg) {
      s_out[w][0][li][dt*16 + lg*4 + reg] = accm[dt][reg] * inv2;
      s_out[w][1][li][dt*16 + lg*4 + reg] = accc[dt][reg] * inv2c;
    }
  __syncthreads();
  const int row = l >> 2;
  const int dc = (l & 3) * 16;
  const int gi = i_base + row;
  const bool zero = (gi == 0);
  float* dsts[2] = {omF, ocF};
#pragma unroll
  for (int tn = 0; tn < 2; ++tn) {
    float* dst = dsts[tn] + ((size_t)bh*SEQ + gi)*DK + dc;
#pragma unroll
    for (int part = 0; part < 4; ++part) {
      float4 v4 = *(const float4*)&s_out[w][tn][row][dc + part*4];
      if (zero) { v4.x = 0.f; v4.y = 0.f; v4.z = 0.f; v4.w = 0.f; }
      *(float4*)(dst + part*4) = v4;
    }
  }
}

// ---------------- output GEMM: d_out[m][n] = sum_k OM[m,k] * Wo[n][k] ----------------
__global__ __launch_bounds__(256) void k_outM(float* wsf,
                                              const float* w_mean, const float* w_cov,
                                              float* outp)
{
  __shared__ __align__(16) unsigned short Ah[4096];
  __shared__ __align__(16) unsigned short Al[4096];
  __shared__ __align__(16) unsigned short Bh[4096];
  __shared__ __align__(16) unsigned short Bl[4096];
  const int y = blockIdx.y;
  const float* A = wsf + (y ? WS_OC : WS_OM);
  const float* W = y ? w_cov : w_mean;
  float* out = outp + (size_t)y * 4194304ull;

  const int tid = threadIdx.x;
  const int l = tid & 63, li = l & 15, lg = l >> 4;
  const int w = tid >> 6, wr = w >> 1, wc = w & 1;
  const int m0 = (blockIdx.x >> 2) * 128;
  const int n0 = (blockIdx.x & 3) * 128;
  const int r0 = tid >> 2, c0 = tid & 3, r1 = r0 + 64;
  const int wo0 = r0*64 + ((c0 ^ ((r0>>1)&3))*16);
  const int wo1 = r1*64 + ((c0 ^ ((r1>>1)&3))*16);
  int roA[4], roB[4];
#pragma unroll
  for (int mi = 0; mi < 4; ++mi) {
    int r  = wr*64 + mi*16 + li;
    roA[mi] = r*64 + ((lg ^ ((r>>1)&3))*16);
    int rn = wc*64 + mi*16 + li;
    roB[mi] = rn*64 + ((lg ^ ((rn>>1)&3))*16);
  }
  const int mA0 = m0 + r0, mA1 = m0 + r1;
  const size_t abase0 = ((size_t)(mA0 >> 9) * NHEAD * SEQ + (mA0 & 511)) * DK;
  const size_t abase1 = ((size_t)(mA1 >> 9) * NHEAD * SEQ + (mA1 & 511)) * DK;
  const float* wp0 = W + (size_t)(n0 + r0)*DMODEL + c0*8;
  const float* wp1 = W + (size_t)(n0 + r1)*DMODEL + c0*8;

  auto aload = [&](size_t abase, int k, float* t8) {
    const float* p = A + abase + (size_t)(k >> 6) * (SEQ*DK) + (k & 63);
    ld8_f32(p, t8);
  };

  uint4 a0h,a0l,a1h,a1l,b0h,b0l,b1h,b1l;
  {
    float t8[8];
    int k0 = c0*8;
    aload(abase0, k0, t8); cvt8(t8, a0h, a0l);
    aload(abase1, k0, t8); cvt8(t8, a1h, a1l);
    ld8_f32(wp0, t8); cvt8(t8, b0h, b0l);
    ld8_f32(wp1, t8); cvt8(t8, b1h, b1l);
  }
  f32x4 acc[4][4];
  f32x4 z = {0.f,0.f,0.f,0.f};
#pragma unroll
  for (int a = 0; a < 4; ++a)
#pragma unroll
    for (int b = 0; b < 4; ++b) acc[a][b] = z;

  for (int kt = 0; kt < DMODEL; kt += 32) {
    __syncthreads();
    *(uint4*)((char*)Ah + wo0) = a0h; *(uint4*)((char*)Al + wo0) = a0l;
    *(uint4*)((char*)Ah + wo1) = a1h; *(uint4*)((char*)Al + wo1) = a1l;
    *(uint4*)((char*)Bh + wo0) = b0h; *(uint4*)((char*)Bl + wo0) = b0l;
    *(uint4*)((char*)Bh + wo1) = b1h; *(uint4*)((char*)Bl + wo1) = b1l;
    __syncthreads();
    if (kt + 32 < DMODEL) {
      float t8[8];
      int kn = kt + 32 + c0*8;
      aload(abase0, kn, t8); cvt8(t8, a0h, a0l);
      aload(abase1, kn, t8); cvt8(t8, a1h, a1l);
      ld8_f32(wp0 + kt + 32, t8); cvt8(t8, b0h, b0l);
      ld8_f32(wp1 + kt + 32, t8); cvt8(t8, b1h, b1l);
    }
    bf16x8 ah[4], alo[4], bh[4], blo[4];
#pragma unroll
    for (int mi = 0; mi < 4; ++mi) {
      ah[mi]  = *(const bf16x8*)((const char*)Ah + roA[mi]);
      alo[mi] = *(const bf16x8*)((const char*)Al + roA[mi]);
      bh[mi]  = *(const bf16x8*)((const char*)Bh + roB[mi]);
      blo[mi] = *(const bf16x8*)((const char*)Bl + roB[mi]);
    }
#pragma unroll
    for (int mi = 0; mi < 4; ++mi)
#pragma unroll
      for (int nj = 0; nj < 4; ++nj) {
        acc[mi][nj] = MFMA32(ah[mi],  bh[nj],  acc[mi][nj]);
        acc[mi][nj] = MFMA32(alo[mi], bh[nj],  acc[mi][nj]);
        acc[mi][nj] = MFMA32(ah[mi],  blo[nj], acc[mi][nj]);
      }
  }
#pragma unroll
  for (int mi = 0; mi < 4; ++mi)
#pragma unroll
    for (int nj = 0; nj < 4; ++nj)
#pragma unroll
      for (int reg = 0; reg < 4; ++reg) {
        int m = m0 + wr*64 + mi*16 + 4*lg + reg;
        int n = n0 + wc*64 + nj*16 + li;
        out[(size_t)m*DMODEL + n] = acc[mi][nj][reg];
      }
}

extern "C" void kernel_launch(void* const* d_in, const int* in_sizes, int n_in,
                              void* d_out, int out_size, void* d_ws, size_t ws_size,
                              hipStream_t stream) {
  (void)in_sizes; (void)n_in; (void)out_size; (void)ws_size;
  float* wsf = (float*)d_ws;

  k_gamma<<<1, 64, 0, stream>>>((const float*)d_in[14], wsf);
  k_projM<<<dim3(256, 6), 256, 0, stream>>>(
      (const float*)d_in[0], (const float*)d_in[1],
      (const float*)d_in[2], (const float*)d_in[3],
      (const float*)d_in[4], (const float*)d_in[5],
      (const float*)d_in[6], (const float*)d_in[7],
      (const float*)d_in[8], (const float*)d_in[9],
      (const float*)d_in[10], (const float*)d_in[11],
      wsf);
  k_sumAB<<<256, 256, 0, stream>>>(wsf);
  k_attn2<<<1024, 256, 0, stream>>>(wsf);
  k_outM<<<dim3(256, 2), 256, 0, stream>>>(wsf, (const float*)d_in[12],
                                           (const float*)d_in[13], (float*)d_out);
}

// Round 7
// 363.142 us; speedup vs baseline: 3.5057x; 1.4012x over previous
//
#include <hip/hip_runtime.h>
#include <hip/hip_bf16.h>

#define SEQ    512
#define DMODEL 512
#define NHEAD  8
#define DK     64
#define BS     16
#define NBH    (BS*NHEAD)       // 128
#define HSZ    (SEQ*DK)         // 32768 per (b,h)

typedef __attribute__((ext_vector_type(8))) short bf16x8;
typedef __attribute__((ext_vector_type(4))) float f32x4;

#define MFMA32(A,B,C) __builtin_amdgcn_mfma_f32_16x16x32_bf16(A,B,C,0,0,0)

// ---------------- workspace layout (fp32 units) ----------------
#define WS_GAM 16ull
#define WS_AQM 256ull
#define WS_AQC (WS_AQM +  65536ull)
#define WS_BKM (WS_AQM + 131072ull)
#define WS_BKC (WS_AQM + 196608ull)
#define WS_AQF (WS_AQM + 262144ull)
#define WS_BKF (WS_AQM + 327680ull)
#define WS_OM  1048576ull
#define WS_OC  (WS_OM + 4194304ull)
#define WS_BF  (WS_OC + 4194304ull)     // bf16 arrays region
#define ARRE   4194304ull               // elems per bf16 array
// bf16 array ids
#define A_QMH 0
#define A_QML 1
#define A_SCH 2
#define A_SCL 3
#define A_KMH 4
#define A_KML 5
#define A_SKH 6
#define A_SKL 7
#define A_VMT 8
#define A_VCT 9

__device__ __forceinline__ unsigned short* warr(float* wsf, int idx) {
  return (unsigned short*)(wsf + WS_BF) + (size_t)idx * ARRE;
}

// ---------- helpers ----------
__device__ __forceinline__ float bf2f(unsigned short h) {
  union { float f; unsigned u; } v; v.u = ((unsigned)h) << 16; return v.f;
}
__device__ __forceinline__ unsigned short f2bf(float f) {
  union { float f; unsigned u; } v; v.f = f;
  unsigned u = v.u;
  u += 0x7FFFu + ((u >> 16) & 1u);   // RNE
  return (unsigned short)(u >> 16);
}
__device__ __forceinline__ void ld8_f32(const float* p, float* v) {
  float4 a = *(const float4*)p; float4 b = *(const float4*)(p+4);
  v[0]=a.x;v[1]=a.y;v[2]=a.z;v[3]=a.w;v[4]=b.x;v[5]=b.y;v[6]=b.z;v[7]=b.w;
}
// fp32[8] -> bf16 hi[8], lo[8] (packed uint4 each)
__device__ __forceinline__ void cvt8(const float* v, uint4& h, uint4& l) {
  unsigned hh[8], ll[8];
#pragma unroll
  for (int e = 0; e < 8; ++e) {
    unsigned short hb = f2bf(v[e]);
    hh[e] = hb;
    ll[e] = f2bf(v[e] - bf2f(hb));
  }
  h.x = hh[0]|(hh[1]<<16); h.y = hh[2]|(hh[3]<<16);
  h.z = hh[4]|(hh[5]<<16); h.w = hh[6]|(hh[7]<<16);
  l.x = ll[0]|(ll[1]<<16); l.y = ll[2]|(ll[3]<<16);
  l.z = ll[4]|(ll[5]<<16); l.w = ll[6]|(ll[7]<<16);
}

__global__ void k_gamma(const float* __restrict__ g_in, float* __restrict__ wsf) {
  int t = threadIdx.x;
  if (t >= NHEAD) return;
  float g = g_in[t];
  float sp = (g > 20.f) ? g : log1pf(expf(g));
  (wsf + WS_GAM)[t] = -sp;
}

// ---------------- projections (fp32 in, hi/lo bf16 3-term MFMA) ----------------
// y: 0 qm, 1 km, 2 qc, 3 kc, 4 vm, 5 vc
__global__ __launch_bounds__(256) void k_projM(
    const float* xqm, const float* xqc, const float* xkm, const float* xkc,
    const float* xvm, const float* xvc,
    const float* wqm, const float* wqc, const float* wkm, const float* wkc,
    const float* wvm, const float* wvc,
    float* wsf)
{
  __shared__ __align__(16) unsigned short Ah[4096];
  __shared__ __align__(16) unsigned short Al[4096];
  __shared__ __align__(16) unsigned short Bh[4096];
  __shared__ __align__(16) unsigned short Bl[4096];
  const int y = blockIdx.y;
  const float* X; const float* W;
  unsigned short *outh = nullptr, *outl = nullptr;
  float* sums = nullptr;
  float qscale = 1.0f; int mode = 0;  // 0 mean, 1 cov, 2 v
  switch (y) {
    case 0: X=xqm; W=wqm; outh=warr(wsf,A_QMH); outl=warr(wsf,A_QML); sums=wsf+WS_AQM; qscale=0.25f; mode=0; break;
    case 1: X=xkm; W=wkm; outh=warr(wsf,A_KMH); outl=warr(wsf,A_KML); sums=wsf+WS_BKM; qscale=1.0f;  mode=0; break;
    case 2: X=xqc; W=wqc; outh=warr(wsf,A_SCH); outl=warr(wsf,A_SCL); sums=wsf+WS_AQC; qscale=0.25f; mode=1; break;
    case 3: X=xkc; W=wkc; outh=warr(wsf,A_SKH); outl=warr(wsf,A_SKL); sums=wsf+WS_BKC; qscale=1.0f;  mode=1; break;
    case 4: X=xvm; W=wvm; outh=warr(wsf,A_VMT); mode=2; break;
    default:X=xvc; W=wvc; outh=warr(wsf,A_VCT); mode=2; break;
  }
  const int tid = threadIdx.x;
  const int l = tid & 63, li = l & 15, lg = l >> 4;
  const int w = tid >> 6, wr = w >> 1, wc = w & 1;
  const int m0 = (blockIdx.x >> 2) * 128;
  const int n0 = (blockIdx.x & 3) * 128;
  const int r0 = tid >> 2, c0 = tid & 3, r1 = r0 + 64;
  const int wo0 = r0*64 + ((c0 ^ ((r0>>1)&3))*16);
  const int wo1 = r1*64 + ((c0 ^ ((r1>>1)&3))*16);
  int roA[4], roB[4];
#pragma unroll
  for (int mi = 0; mi < 4; ++mi) {
    int r  = wr*64 + mi*16 + li;
    roA[mi] = r*64 + ((lg ^ ((r>>1)&3))*16);
    int rn = wc*64 + mi*16 + li;
    roB[mi] = rn*64 + ((lg ^ ((rn>>1)&3))*16);
  }
  const float* xp0 = X + (size_t)(m0+r0)*DMODEL + c0*8;
  const float* xp1 = X + (size_t)(m0+r1)*DMODEL + c0*8;
  const float* wp0 = W + (size_t)(n0+r0)*DMODEL + c0*8;
  const float* wp1 = W + (size_t)(n0+r1)*DMODEL + c0*8;
  uint4 a0h,a0l,a1h,a1l,b0h,b0l,b1h,b1l;
  {
    float t8[8];
    ld8_f32(xp0, t8); cvt8(t8, a0h, a0l);
    ld8_f32(xp1, t8); cvt8(t8, a1h, a1l);
    ld8_f32(wp0, t8); cvt8(t8, b0h, b0l);
    ld8_f32(wp1, t8); cvt8(t8, b1h, b1l);
  }
  f32x4 acc[4][4];
  f32x4 z = {0.f,0.f,0.f,0.f};
#pragma unroll
  for (int a = 0; a < 4; ++a)
#pragma unroll
    for (int b = 0; b < 4; ++b) acc[a][b] = z;

  for (int kt = 0; kt < DMODEL; kt += 32) {
    __syncthreads();
    *(uint4*)((char*)Ah + wo0) = a0h; *(uint4*)((char*)Al + wo0) = a0l;
    *(uint4*)((char*)Ah + wo1) = a1h; *(uint4*)((char*)Al + wo1) = a1l;
    *(uint4*)((char*)Bh + wo0) = b0h; *(uint4*)((char*)Bl + wo0) = b0l;
    *(uint4*)((char*)Bh + wo1) = b1h; *(uint4*)((char*)Bl + wo1) = b1l;
    __syncthreads();
    if (kt + 32 < DMODEL) {
      float t8[8];
      ld8_f32(xp0 + kt + 32, t8); cvt8(t8, a0h, a0l);
      ld8_f32(xp1 + kt + 32, t8); cvt8(t8, a1h, a1l);
      ld8_f32(wp0 + kt + 32, t8); cvt8(t8, b0h, b0l);
      ld8_f32(wp1 + kt + 32, t8); cvt8(t8, b1h, b1l);
    }
    bf16x8 ah[4], alo[4], bh[4], blo[4];
#pragma unroll
    for (int mi = 0; mi < 4; ++mi) {
      ah[mi]  = *(const bf16x8*)((const char*)Ah + roA[mi]);
      alo[mi] = *(const bf16x8*)((const char*)Al + roA[mi]);
      bh[mi]  = *(const bf16x8*)((const char*)Bh + roB[mi]);
      blo[mi] = *(const bf16x8*)((const char*)Bl + roB[mi]);
    }
#pragma unroll
    for (int mi = 0; mi < 4; ++mi)
#pragma unroll
      for (int nj = 0; nj < 4; ++nj) {
        acc[mi][nj] = MFMA32(ah[mi],  bh[nj],  acc[mi][nj]);
        acc[mi][nj] = MFMA32(alo[mi], bh[nj],  acc[mi][nj]);
        acc[mi][nj] = MFMA32(ah[mi],  blo[nj], acc[mi][nj]);
      }
  }

  const int head = ((n0 >> 6) + wc);
  if (mode <= 1) {
#pragma unroll
    for (int mi = 0; mi < 4; ++mi)
#pragma unroll
      for (int reg = 0; reg < 4; ++reg) {
        float rs = 0.f;
#pragma unroll
        for (int nj = 0; nj < 4; ++nj) {
          float v = acc[mi][nj][reg];
          rs += (mode == 0) ? v*v : v;
        }
        rs += __shfl_xor(rs, 1); rs += __shfl_xor(rs, 2);
        rs += __shfl_xor(rs, 4); rs += __shfl_xor(rs, 8);
        if (li == 0) {
          int m = m0 + wr*64 + mi*16 + 4*lg + reg;
          sums[((size_t)(m >> 9)*NHEAD + head)*SEQ + (m & 511)] = rs;
        }
      }
#pragma unroll
    for (int mi = 0; mi < 4; ++mi)
#pragma unroll
      for (int nj = 0; nj < 4; ++nj)
#pragma unroll
        for (int reg = 0; reg < 4; ++reg) {
          float v = acc[mi][nj][reg];
          if (mode == 1) v = sqrtf(fmaxf(v, 1e-24f));
          v *= qscale;
          unsigned short h16 = f2bf(v);
          unsigned short l16 = f2bf(v - bf2f(h16));
          int m = m0 + wr*64 + mi*16 + 4*lg + reg;
          int n = n0 + wc*64 + nj*16 + li;
          size_t dst = ((size_t)((m >> 9)*NHEAD + (n >> 6))*SEQ + (m & 511))*DK + (n & 63);
          outh[dst] = h16; outl[dst] = l16;
        }
  } else {
    // V: transposed [bh][d][s], 4 consecutive s per store
#pragma unroll
    for (int mi = 0; mi < 4; ++mi)
#pragma unroll
      for (int nj = 0; nj < 4; ++nj) {
        int mb = m0 + wr*64 + mi*16 + 4*lg;
        int n = n0 + wc*64 + nj*16 + li;
        int b = mb >> 9, s = mb & 511, d = n & 63;
        unsigned e0 = f2bf(acc[mi][nj][0]);
        unsigned e1 = f2bf(acc[mi][nj][1]);
        unsigned e2 = f2bf(acc[mi][nj][2]);
        unsigned e3 = f2bf(acc[mi][nj][3]);
        uint2 pk; pk.x = e0 | (e1 << 16); pk.y = e2 | (e3 << 16);
        *(uint2*)(outh + ((size_t)(b*NHEAD + head)*DK + d)*SEQ + s) = pk;
      }
  }
}

__global__ void k_sumAB(float* wsf) {
  int i = blockIdx.x * 256 + threadIdx.x;
  if (i < NBH*SEQ) {
    (wsf+WS_AQF)[i] = 0.125f * ((wsf+WS_AQM)[i] + (wsf+WS_AQC)[i]);
    (wsf+WS_BKF)[i] = 0.125f * ((wsf+WS_BKM)[i] + (wsf+WS_BKC)[i]);
  }
}

// ---------------- flash-style fused attention ----------------
// 2 independent waves per block; wave handles row-tile pair (p, 31-p): uniform 33 j-tiles.
__global__ __launch_bounds__(128) void k_attn2(float* wsf)
{
  __shared__ float s_bk[SEQ];

  const unsigned short* qmh = warr(wsf, A_QMH);
  const unsigned short* qml = warr(wsf, A_QML);
  const unsigned short* sch = warr(wsf, A_SCH);
  const unsigned short* scl = warr(wsf, A_SCL);
  const unsigned short* kmh = warr(wsf, A_KMH);
  const unsigned short* kml = warr(wsf, A_KML);
  const unsigned short* skh = warr(wsf, A_SKH);
  const unsigned short* skl = warr(wsf, A_SKL);
  const unsigned short* vmT = warr(wsf, A_VMT);
  const unsigned short* vcT = warr(wsf, A_VCT);
  float* omF = wsf + WS_OM;
  float* ocF = wsf + WS_OC;
  const float* AqF = wsf + WS_AQF;
  const float* BkF = wsf + WS_BKF;

  const int tid = threadIdx.x;
  const int l = tid & 63, li = l & 15, lg = l >> 4;
  const int w = tid >> 6;                 // 0..1
  const int bh = blockIdx.x >> 3;
  const int pp = (blockIdx.x & 7) * 2 + w;  // pair id 0..15
  const float gam = (wsf + WS_GAM)[bh & (NHEAD-1)];

  for (int idx = tid; idx < SEQ; idx += 128) s_bk[idx] = BkF[(size_t)bh*SEQ + idx];
  __syncthreads();

  for (int half = 0; half < 2; ++half) {
    const int rt = half ? (31 - pp) : pp;     // row-tile 0..31
    const int i = rt*16 + li;
    const int ntile = rt + 1;
    const float aq = AqF[(size_t)bh*SEQ + i];

    // Q fragments (B-operand): [part][ks][hi/lo]
    bf16x8 qf[8];
    {
      const unsigned short* qb[4] = {qmh, qml, sch, scl};
#pragma unroll
      for (int part = 0; part < 2; ++part)
#pragma unroll
        for (int hl = 0; hl < 2; ++hl)
#pragma unroll
          for (int ks = 0; ks < 2; ++ks)
            qf[part*4 + ks*2 + hl] =
              *(const bf16x8*)(qb[part*2+hl] + ((size_t)bh*SEQ + i)*DK + ks*32 + lg*8);
    }

    auto score_tile = [&](int t, float* s) {
      const int j0 = t*16;
      f32x4 accA = {0.f,0.f,0.f,0.f};   // hi*hi chain
      f32x4 accB = {0.f,0.f,0.f,0.f};   // correction chain
      const size_t krow = ((size_t)bh*SEQ + j0 + li)*DK + lg*8;
#pragma unroll
      for (int part = 0; part < 2; ++part) {
        const unsigned short* khp = part ? skh : kmh;
        const unsigned short* klp = part ? skl : kml;
#pragma unroll
        for (int ks = 0; ks < 2; ++ks) {
          bf16x8 kh = *(const bf16x8*)(khp + krow + ks*32);
          bf16x8 kl = *(const bf16x8*)(klp + krow + ks*32);
          accA = MFMA32(kh, qf[part*4+ks*2+0], accA);
          accB = MFMA32(kl, qf[part*4+ks*2+0], accB);
          accB = MFMA32(kh, qf[part*4+ks*2+1], accB);
        }
      }
      const float4 bk4 = *(const float4*)&s_bk[j0 + lg*4];
      float bks[4] = {bk4.x, bk4.y, bk4.z, bk4.w};
#pragma unroll
      for (int r = 0; r < 4; ++r) {
        int j = j0 + lg*4 + r;
        float v = (accA[r] + accB[r]) - aq - bks[r];
        s[r] = (j > i) ? -3.0e38f : v;
      }
    };

    // ---- pass 1: softmax-1 stats ----
    float m1 = -3.0e38f, tot = 0.f;
    for (int t = 0; t < ntile; ++t) {
      float s[4]; score_tile(t, s);
      float tm = fmaxf(fmaxf(s[0], s[1]), fmaxf(s[2], s[3]));
      tm = fmaxf(tm, __shfl_xor(tm, 16));
      tm = fmaxf(tm, __shfl_xor(tm, 32));
      float m1n = fmaxf(m1, tm);
      float lsum = __expf(s[0]-m1n) + __expf(s[1]-m1n) + __expf(s[2]-m1n) + __expf(s[3]-m1n);
      lsum += __shfl_xor(lsum, 16); lsum += __shfl_xor(lsum, 32);
      tot = tot * __expf(m1 - m1n) + lsum;
      m1 = m1n;
    }
    const float invtot = 1.0f / tot;

    // ---- pass 2: scan + online softmax-2 + PV ----
    f32x4 accm[4], accc[4];
    {
      f32x4 z = {0.f,0.f,0.f,0.f};
#pragma unroll
      for (int dt = 0; dt < 4; ++dt) { accm[dt] = z; accc[dt] = z; }
    }
    float run = 0.f, m2 = -3.0e38f, sum2 = 0.f;

    auto scan_tile = [&](int t, float* s2) {
      float s[4]; score_tile(t, s);
      float e0 = __expf(s[0]-m1), e1 = __expf(s[1]-m1),
            e2 = __expf(s[2]-m1), e3 = __expf(s[3]-m1);
      float p0 = e0, p1 = p0+e1, p2 = p1+e2, p3 = p2+e3;
      float lt = p3;
      float a = __shfl_up(lt, 16), b = __shfl_up(lt, 32), c = __shfl_up(lt, 48);
      float excl = (lg >= 1 ? a : 0.f) + (lg >= 2 ? b : 0.f) + (lg >= 3 ? c : 0.f);
      float base = run + excl;
      float cums[4] = {base+p0, base+p1, base+p2, base+p3};
      float ttr = lt;
      ttr += __shfl_xor(ttr, 16); ttr += __shfl_xor(ttr, 32);
      run += ttr;
#pragma unroll
      for (int r = 0; r < 4; ++r) {
        int j = t*16 + lg*4 + r;
        float rem = fmaxf(tot - cums[r], 0.f) * invtot;
        float pos = fmaxf((float)(i - j), 0.f);
        float dist = sqrtf(rem * pos);
        float eff = fmaxf(__expf(dist * gam), 1e-5f);
        s2[r] = (j > i) ? -3.0e38f : s[r] * eff;
      }
    };

    for (int t0 = 0; t0 < ntile; t0 += 2) {
      float s2A[4], s2B[4];
      scan_tile(t0, s2A);
      const bool hasB = (t0 + 1) < ntile;
      if (hasB) scan_tile(t0+1, s2B);
      else { s2B[0]=s2B[1]=s2B[2]=s2B[3] = -3.0e38f; }
      float mt = fmaxf(fmaxf(fmaxf(s2A[0],s2A[1]), fmaxf(s2A[2],s2A[3])),
                       fmaxf(fmaxf(s2B[0],s2B[1]), fmaxf(s2B[2],s2B[3])));
      mt = fmaxf(mt, __shfl_xor(mt, 16));
      mt = fmaxf(mt, __shfl_xor(mt, 32));
      float m2n = fmaxf(m2, mt);
      float scale = __expf(m2 - m2n);
      float scale2 = scale * scale;
#pragma unroll
      for (int dt = 0; dt < 4; ++dt) { accm[dt] *= scale; accc[dt] *= scale2; }
      float pA[4], pB[4];
#pragma unroll
      for (int r = 0; r < 4; ++r) { pA[r] = __expf(s2A[r]-m2n); pB[r] = __expf(s2B[r]-m2n); }
      float ps = pA[0]+pA[1]+pA[2]+pA[3] + pB[0]+pB[1]+pB[2]+pB[3];
      ps += __shfl_xor(ps, 16); ps += __shfl_xor(ps, 32);
      sum2 = sum2 * scale + ps;
      m2 = m2n;
      bf16x8 pbm, pbc;
#pragma unroll
      for (int r = 0; r < 4; ++r) {
        pbm[r]   = (short)f2bf(pA[r]);
        pbm[4+r] = (short)f2bf(pB[r]);
        pbc[r]   = (short)f2bf(pA[r]*pA[r]);
        pbc[4+r] = (short)f2bf(pB[r]*pB[r]);
      }
      const int j0A = t0*16;
      const int j0B = hasB ? j0A + 16 : j0A;
      union V16 { struct { uint2 lo, hi; } u; bf16x8 v; };
#pragma unroll
      for (int dt = 0; dt < 4; ++dt) {
        const size_t vrow = ((size_t)bh*DK + dt*16 + li)*SEQ;
        V16 vm_, vc_;
        vm_.u.lo = *(const uint2*)(vmT + vrow + j0A + lg*4);
        vm_.u.hi = *(const uint2*)(vmT + vrow + j0B + lg*4);
        vc_.u.lo = *(const uint2*)(vcT + vrow + j0A + lg*4);
        vc_.u.hi = *(const uint2*)(vcT + vrow + j0B + lg*4);
        accm[dt] = MFMA32(vm_.v, pbm, accm[dt]);
        accc[dt] = MFMA32(vc_.v, pbc, accc[dt]);
      }
    }

    // ---- finalize: direct global stores (D-frag is float4-contiguous in d) ----
    const float inv2 = 1.0f / sum2;
    const float inv2c = inv2 * inv2;
    const bool zero = (i == 0);
    float* om_p = omF + ((size_t)bh*SEQ + i)*DK;
    float* oc_p = ocF + ((size_t)bh*SEQ + i)*DK;
#pragma unroll
    for (int dt = 0; dt < 4; ++dt) {
      float4 vm4, vc4;
      vm4.x = accm[dt][0]*inv2;  vm4.y = accm[dt][1]*inv2;
      vm4.z = accm[dt][2]*inv2;  vm4.w = accm[dt][3]*inv2;
      vc4.x = accc[dt][0]*inv2c; vc4.y = accc[dt][1]*inv2c;
      vc4.z = accc[dt][2]*inv2c; vc4.w = accc[dt][3]*inv2c;
      if (zero) { vm4 = make_float4(0.f,0.f,0.f,0.f); vc4 = vm4; }
      *(float4*)(om_p + dt*16 + lg*4) = vm4;
      *(float4*)(oc_p + dt*16 + lg*4) = vc4;
    }
  }
}

// ---------------- output GEMM: d_out[m][n] = sum_k OM[m,k] * Wo[n][k] ----------------
__global__ __launch_bounds__(256) void k_outM(float* wsf,
                                              const float* w_mean, const float* w_cov,
                                              float* outp)
{
  __shared__ __align__(16) unsigned short Ah[4096];
  __shared__ __align__(16) unsigned short Al[4096];
  __shared__ __align__(16) unsigned short Bh[4096];
  __shared__ __align__(16) unsigned short Bl[4096];
  const int y = blockIdx.y;
  const float* A = wsf + (y ? WS_OC : WS_OM);
  const float* W = y ? w_cov : w_mean;
  float* out = outp + (size_t)y * 4194304ull;

  const int tid = threadIdx.x;
  const int l = tid & 63, li = l & 15, lg = l >> 4;
  const int w = tid >> 6, wr = w >> 1, wc = w & 1;
  const int m0 = (blockIdx.x >> 2) * 128;
  const int n0 = (blockIdx.x & 3) * 128;
  const int r0 = tid >> 2, c0 = tid & 3, r1 = r0 + 64;
  const int wo0 = r0*64 + ((c0 ^ ((r0>>1)&3))*16);
  const int wo1 = r1*64 + ((c0 ^ ((r1>>1)&3))*16);
  int roA[4], roB[4];
#pragma unroll
  for (int mi = 0; mi < 4; ++mi) {
    int r  = wr*64 + mi*16 + li;
    roA[mi] = r*64 + ((lg ^ ((r>>1)&3))*16);
    int rn = wc*64 + mi*16 + li;
    roB[mi] = rn*64 + ((lg ^ ((rn>>1)&3))*16);
  }
  const int mA0 = m0 + r0, mA1 = m0 + r1;
  const size_t abase0 = ((size_t)(mA0 >> 9) * NHEAD * SEQ + (mA0 & 511)) * DK;
  const size_t abase1 = ((size_t)(mA1 >> 9) * NHEAD * SEQ + (mA1 & 511)) * DK;
  const float* wp0 = W + (size_t)(n0 + r0)*DMODEL + c0*8;
  const float* wp1 = W + (size_t)(n0 + r1)*DMODEL + c0*8;

  auto aload = [&](size_t abase, int k, float* t8) {
    const float* p = A + abase + (size_t)(k >> 6) * (SEQ*DK) + (k & 63);
    ld8_f32(p, t8);
  };

  uint4 a0h,a0l,a1h,a1l,b0h,b0l,b1h,b1l;
  {
    float t8[8];
    int k0 = c0*8;
    aload(abase0, k0, t8); cvt8(t8, a0h, a0l);
    aload(abase1, k0, t8); cvt8(t8, a1h, a1l);
    ld8_f32(wp0, t8); cvt8(t8, b0h, b0l);
    ld8_f32(wp1, t8); cvt8(t8, b1h, b1l);
  }
  f32x4 acc[4][4];
  f32x4 z = {0.f,0.f,0.f,0.f};
#pragma unroll
  for (int a = 0; a < 4; ++a)
#pragma unroll
    for (int b = 0; b < 4; ++b) acc[a][b] = z;

  for (int kt = 0; kt < DMODEL; kt += 32) {
    __syncthreads();
    *(uint4*)((char*)Ah + wo0) = a0h; *(uint4*)((char*)Al + wo0) = a0l;
    *(uint4*)((char*)Ah + wo1) = a1h; *(uint4*)((char*)Al + wo1) = a1l;
    *(uint4*)((char*)Bh + wo0) = b0h; *(uint4*)((char*)Bl + wo0) = b0l;
    *(uint4*)((char*)Bh + wo1) = b1h; *(uint4*)((char*)Bl + wo1) = b1l;
    __syncthreads();
    if (kt + 32 < DMODEL) {
      float t8[8];
      int kn = kt + 32 + c0*8;
      aload(abase0, kn, t8); cvt8(t8, a0h, a0l);
      aload(abase1, kn, t8); cvt8(t8, a1h, a1l);
      ld8_f32(wp0 + kt + 32, t8); cvt8(t8, b0h, b0l);
      ld8_f32(wp1 + kt + 32, t8); cvt8(t8, b1h, b1l);
    }
    bf16x8 ah[4], alo[4], bh[4], blo[4];
#pragma unroll
    for (int mi = 0; mi < 4; ++mi) {
      ah[mi]  = *(const bf16x8*)((const char*)Ah + roA[mi]);
      alo[mi] = *(const bf16x8*)((const char*)Al + roA[mi]);
      bh[mi]  = *(const bf16x8*)((const char*)Bh + roB[mi]);
      blo[mi] = *(const bf16x8*)((const char*)Bl + roB[mi]);
    }
#pragma unroll
    for (int mi = 0; mi < 4; ++mi)
#pragma unroll
      for (int nj = 0; nj < 4; ++nj) {
        acc[mi][nj] = MFMA32(ah[mi],  bh[nj],  acc[mi][nj]);
        acc[mi][nj] = MFMA32(alo[mi], bh[nj],  acc[mi][nj]);
        acc[mi][nj] = MFMA32(ah[mi],  blo[nj], acc[mi][nj]);
      }
  }
#pragma unroll
  for (int mi = 0; mi < 4; ++mi)
#pragma unroll
    for (int nj = 0; nj < 4; ++nj)
#pragma unroll
      for (int reg = 0; reg < 4; ++reg) {
        int m = m0 + wr*64 + mi*16 + 4*lg + reg;
        int n = n0 + wc*64 + nj*16 + li;
        out[(size_t)m*DMODEL + n] = acc[mi][nj][reg];
      }
}

extern "C" void kernel_launch(void* const* d_in, const int* in_sizes, int n_in,
                              void* d_out, int out_size, void* d_ws, size_t ws_size,
                              hipStream_t stream) {
  (void)in_sizes; (void)n_in; (void)out_size; (void)ws_size;
  float* wsf = (float*)d_ws;

  k_gamma<<<1, 64, 0, stream>>>((const float*)d_in[14], wsf);
  k_projM<<<dim3(256, 6), 256, 0, stream>>>(
      (const float*)d_in[0], (const float*)d_in[1],
      (const float*)d_in[2], (const float*)d_in[3],
      (const float*)d_in[4], (const float*)d_in[5],
      (const float*)d_in[6], (const float*)d_in[7],
      (const float*)d_in[8], (const float*)d_in[9],
      (const float*)d_in[10], (const float*)d_in[11],
      wsf);
  k_sumAB<<<256, 256, 0, stream>>>(wsf);
  k_attn2<<<1024, 128, 0, stream>>>(wsf);
  k_outM<<<dim3(256, 2), 256, 0, stream>>>(wsf, (const float*)d_in[12],
                                           (const float*)d_in[13], (float*)d_out);
}

// Round 8
// 305.935 us; speedup vs baseline: 4.1612x; 1.1870x over previous
//
#include <hip/hip_runtime.h>
#include <hip/hip_bf16.h>

#define SEQ    512
#define DMODEL 512
#define NHEAD  8
#define DK     64
#define BS     16
#define NBH    (BS*NHEAD)       // 128
#define HSZ    (SEQ*DK)         // 32768 per (b,h)

typedef __attribute__((ext_vector_type(8))) short bf16x8;
typedef __attribute__((ext_vector_type(4))) float f32x4;

#define MFMA32(A,B,C) __builtin_amdgcn_mfma_f32_16x16x32_bf16(A,B,C,0,0,0)

// ---------------- workspace layout (fp32 units) ----------------
#define WS_GAM 16ull
#define WS_AQM 256ull
#define WS_AQC (WS_AQM +  65536ull)
#define WS_BKM (WS_AQM + 131072ull)
#define WS_BKC (WS_AQM + 196608ull)
#define WS_AQF (WS_AQM + 262144ull)
#define WS_BKF (WS_AQM + 327680ull)
#define WS_OM  1048576ull
#define WS_OC  (WS_OM + 4194304ull)
#define WS_BF  (WS_OC + 4194304ull)     // bf16 arrays region
#define ARRE   4194304ull               // elems per bf16 array
// bf16 array ids
#define A_QMH 0
#define A_QML 1
#define A_SCH 2
#define A_SCL 3
#define A_KMH 4
#define A_KML 5
#define A_SKH 6
#define A_SKL 7
#define A_VMT 8
#define A_VCT 9

__device__ __forceinline__ unsigned short* warr(float* wsf, int idx) {
  return (unsigned short*)(wsf + WS_BF) + (size_t)idx * ARRE;
}

// ---------- helpers ----------
__device__ __forceinline__ float bf2f(unsigned short h) {
  union { float f; unsigned u; } v; v.u = ((unsigned)h) << 16; return v.f;
}
__device__ __forceinline__ unsigned short f2bf(float f) {
  union { float f; unsigned u; } v; v.f = f;
  unsigned u = v.u;
  u += 0x7FFFu + ((u >> 16) & 1u);   // RNE
  return (unsigned short)(u >> 16);
}
__device__ __forceinline__ void ld8_f32(const float* p, float* v) {
  float4 a = *(const float4*)p; float4 b = *(const float4*)(p+4);
  v[0]=a.x;v[1]=a.y;v[2]=a.z;v[3]=a.w;v[4]=b.x;v[5]=b.y;v[6]=b.z;v[7]=b.w;
}
// fp32[8] -> bf16 hi[8], lo[8] (packed uint4 each)
__device__ __forceinline__ void cvt8(const float* v, uint4& h, uint4& l) {
  unsigned hh[8], ll[8];
#pragma unroll
  for (int e = 0; e < 8; ++e) {
    unsigned short hb = f2bf(v[e]);
    hh[e] = hb;
    ll[e] = f2bf(v[e] - bf2f(hb));
  }
  h.x = hh[0]|(hh[1]<<16); h.y = hh[2]|(hh[3]<<16);
  h.z = hh[4]|(hh[5]<<16); h.w = hh[6]|(hh[7]<<16);
  l.x = ll[0]|(ll[1]<<16); l.y = ll[2]|(ll[3]<<16);
  l.z = ll[4]|(ll[5]<<16); l.w = ll[6]|(ll[7]<<16);
}

__global__ void k_gamma(const float* __restrict__ g_in, float* __restrict__ wsf) {
  int t = threadIdx.x;
  if (t >= NHEAD) return;
  float g = g_in[t];
  float sp = (g > 20.f) ? g : log1pf(expf(g));
  (wsf + WS_GAM)[t] = -sp;
}

// ---------------- projections (fp32 in, hi/lo bf16 3-term MFMA) ----------------
// y: 0 qm, 1 km, 2 qc, 3 kc, 4 vm, 5 vc
__global__ __launch_bounds__(256) void k_projM(
    const float* xqm, const float* xqc, const float* xkm, const float* xkc,
    const float* xvm, const float* xvc,
    const float* wqm, const float* wqc, const float* wkm, const float* wkc,
    const float* wvm, const float* wvc,
    float* wsf)
{
  __shared__ __align__(16) unsigned short Ah[4096];
  __shared__ __align__(16) unsigned short Al[4096];
  __shared__ __align__(16) unsigned short Bh[4096];
  __shared__ __align__(16) unsigned short Bl[4096];
  const int y = blockIdx.y;
  const float* X; const float* W;
  unsigned short *outh = nullptr, *outl = nullptr;
  float* sums = nullptr;
  float qscale = 1.0f; int mode = 0;  // 0 mean, 1 cov, 2 v
  switch (y) {
    case 0: X=xqm; W=wqm; outh=warr(wsf,A_QMH); outl=warr(wsf,A_QML); sums=wsf+WS_AQM; qscale=0.25f; mode=0; break;
    case 1: X=xkm; W=wkm; outh=warr(wsf,A_KMH); outl=nullptr;         sums=wsf+WS_BKM; qscale=1.0f;  mode=0; break;
    case 2: X=xqc; W=wqc; outh=warr(wsf,A_SCH); outl=warr(wsf,A_SCL); sums=wsf+WS_AQC; qscale=0.25f; mode=1; break;
    case 3: X=xkc; W=wkc; outh=warr(wsf,A_SKH); outl=nullptr;         sums=wsf+WS_BKC; qscale=1.0f;  mode=1; break;
    case 4: X=xvm; W=wvm; outh=warr(wsf,A_VMT); mode=2; break;
    default:X=xvc; W=wvc; outh=warr(wsf,A_VCT); mode=2; break;
  }
  const int tid = threadIdx.x;
  const int l = tid & 63, li = l & 15, lg = l >> 4;
  const int w = tid >> 6, wr = w >> 1, wc = w & 1;
  const int m0 = (blockIdx.x >> 2) * 128;
  const int n0 = (blockIdx.x & 3) * 128;
  const int r0 = tid >> 2, c0 = tid & 3, r1 = r0 + 64;
  const int wo0 = r0*64 + ((c0 ^ ((r0>>1)&3))*16);
  const int wo1 = r1*64 + ((c0 ^ ((r1>>1)&3))*16);
  int roA[4], roB[4];
#pragma unroll
  for (int mi = 0; mi < 4; ++mi) {
    int r  = wr*64 + mi*16 + li;
    roA[mi] = r*64 + ((lg ^ ((r>>1)&3))*16);
    int rn = wc*64 + mi*16 + li;
    roB[mi] = rn*64 + ((lg ^ ((rn>>1)&3))*16);
  }
  const float* xp0 = X + (size_t)(m0+r0)*DMODEL + c0*8;
  const float* xp1 = X + (size_t)(m0+r1)*DMODEL + c0*8;
  const float* wp0 = W + (size_t)(n0+r0)*DMODEL + c0*8;
  const float* wp1 = W + (size_t)(n0+r1)*DMODEL + c0*8;
  uint4 a0h,a0l,a1h,a1l,b0h,b0l,b1h,b1l;
  {
    float t8[8];
    ld8_f32(xp0, t8); cvt8(t8, a0h, a0l);
    ld8_f32(xp1, t8); cvt8(t8, a1h, a1l);
    ld8_f32(wp0, t8); cvt8(t8, b0h, b0l);
    ld8_f32(wp1, t8); cvt8(t8, b1h, b1l);
  }
  f32x4 acc[4][4];
  f32x4 z = {0.f,0.f,0.f,0.f};
#pragma unroll
  for (int a = 0; a < 4; ++a)
#pragma unroll
    for (int b = 0; b < 4; ++b) acc[a][b] = z;

  for (int kt = 0; kt < DMODEL; kt += 32) {
    __syncthreads();
    *(uint4*)((char*)Ah + wo0) = a0h; *(uint4*)((char*)Al + wo0) = a0l;
    *(uint4*)((char*)Ah + wo1) = a1h; *(uint4*)((char*)Al + wo1) = a1l;
    *(uint4*)((char*)Bh + wo0) = b0h; *(uint4*)((char*)Bl + wo0) = b0l;
    *(uint4*)((char*)Bh + wo1) = b1h; *(uint4*)((char*)Bl + wo1) = b1l;
    __syncthreads();
    if (kt + 32 < DMODEL) {
      float t8[8];
      ld8_f32(xp0 + kt + 32, t8); cvt8(t8, a0h, a0l);
      ld8_f32(xp1 + kt + 32, t8); cvt8(t8, a1h, a1l);
      ld8_f32(wp0 + kt + 32, t8); cvt8(t8, b0h, b0l);
      ld8_f32(wp1 + kt + 32, t8); cvt8(t8, b1h, b1l);
    }
    bf16x8 ah[4], alo[4], bh[4], blo[4];
#pragma unroll
    for (int mi = 0; mi < 4; ++mi) {
      ah[mi]  = *(const bf16x8*)((const char*)Ah + roA[mi]);
      alo[mi] = *(const bf16x8*)((const char*)Al + roA[mi]);
      bh[mi]  = *(const bf16x8*)((const char*)Bh + roB[mi]);
      blo[mi] = *(const bf16x8*)((const char*)Bl + roB[mi]);
    }
#pragma unroll
    for (int mi = 0; mi < 4; ++mi)
#pragma unroll
      for (int nj = 0; nj < 4; ++nj) {
        acc[mi][nj] = MFMA32(ah[mi],  bh[nj],  acc[mi][nj]);
        acc[mi][nj] = MFMA32(alo[mi], bh[nj],  acc[mi][nj]);
        acc[mi][nj] = MFMA32(ah[mi],  blo[nj], acc[mi][nj]);
      }
  }

  const int head = ((n0 >> 6) + wc);
  if (mode <= 1) {
#pragma unroll
    for (int mi = 0; mi < 4; ++mi)
#pragma unroll
      for (int reg = 0; reg < 4; ++reg) {
        float rs = 0.f;
#pragma unroll
        for (int nj = 0; nj < 4; ++nj) {
          float v = acc[mi][nj][reg];
          rs += (mode == 0) ? v*v : v;
        }
        rs += __shfl_xor(rs, 1); rs += __shfl_xor(rs, 2);
        rs += __shfl_xor(rs, 4); rs += __shfl_xor(rs, 8);
        if (li == 0) {
          int m = m0 + wr*64 + mi*16 + 4*lg + reg;
          sums[((size_t)(m >> 9)*NHEAD + head)*SEQ + (m & 511)] = rs;
        }
      }
#pragma unroll
    for (int mi = 0; mi < 4; ++mi)
#pragma unroll
      for (int nj = 0; nj < 4; ++nj)
#pragma unroll
        for (int reg = 0; reg < 4; ++reg) {
          float v = acc[mi][nj][reg];
          if (mode == 1) v = sqrtf(fmaxf(v, 1e-24f));
          v *= qscale;
          unsigned short h16 = f2bf(v);
          int m = m0 + wr*64 + mi*16 + 4*lg + reg;
          int n = n0 + wc*64 + nj*16 + li;
          size_t dst = ((size_t)((m >> 9)*NHEAD + (n >> 6))*SEQ + (m & 511))*DK + (n & 63);
          outh[dst] = h16;
          if (outl) outl[dst] = f2bf(v - bf2f(h16));
        }
  } else {
    // V: transposed [bh][d][s], 4 consecutive s per store
#pragma unroll
    for (int mi = 0; mi < 4; ++mi)
#pragma unroll
      for (int nj = 0; nj < 4; ++nj) {
        int mb = m0 + wr*64 + mi*16 + 4*lg;
        int n = n0 + wc*64 + nj*16 + li;
        int b = mb >> 9, s = mb & 511, d = n & 63;
        unsigned e0 = f2bf(acc[mi][nj][0]);
        unsigned e1 = f2bf(acc[mi][nj][1]);
        unsigned e2 = f2bf(acc[mi][nj][2]);
        unsigned e3 = f2bf(acc[mi][nj][3]);
        uint2 pk; pk.x = e0 | (e1 << 16); pk.y = e2 | (e3 << 16);
        *(uint2*)(outh + ((size_t)(b*NHEAD + head)*DK + d)*SEQ + s) = pk;
      }
  }
}

__global__ void k_sumAB(float* wsf) {
  int i = blockIdx.x * 256 + threadIdx.x;
  if (i < NBH*SEQ) {
    (wsf+WS_AQF)[i] = 0.125f * ((wsf+WS_AQM)[i] + (wsf+WS_AQC)[i]);
    (wsf+WS_BKF)[i] = 0.125f * ((wsf+WS_BKM)[i] + (wsf+WS_BKC)[i]);
  }
}

// ---------------- flash-style fused attention, split-j ----------------
// block = (bh, row-tile rt), 2 waves split the j-tile range; XCD-affine swizzle.
__global__ __launch_bounds__(128) void k_attn2(float* wsf)
{
  __shared__ float s_bk[SEQ];
  __shared__ float s_ex[2][2][16];
  __shared__ __align__(16) float s_acc[64][33];

  const unsigned short* qmh = warr(wsf, A_QMH);
  const unsigned short* qml = warr(wsf, A_QML);
  const unsigned short* sch = warr(wsf, A_SCH);
  const unsigned short* scl = warr(wsf, A_SCL);
  const unsigned short* kmh = warr(wsf, A_KMH);
  const unsigned short* skh = warr(wsf, A_SKH);
  const unsigned short* vmT = warr(wsf, A_VMT);
  const unsigned short* vcT = warr(wsf, A_VCT);
  float* omF = wsf + WS_OM;
  float* ocF = wsf + WS_OC;
  const float* AqF = wsf + WS_AQF;
  const float* BkF = wsf + WS_BKF;

  const int tid = threadIdx.x;
  const int l = tid & 63, li = l & 15, lg = l >> 4;
  const int w = tid >> 6;                    // 0..1
  // swizzle: xcd-affine bh, heavy row-tiles first (LPT)
  const int blk = blockIdx.x;                // 0..4095
  const int xcd = blk & 7;
  const int q   = blk >> 3;                  // 0..511
  const int bh  = xcd*16 + (q & 15);
  const int rt  = 31 - (q >> 4);             // row-tile 0..31
  const int i = rt*16 + li;
  const int ntile = rt + 1;
  const int h0 = (ntile + 1) >> 1;           // wave0: [0,h0), wave1: [h0,ntile)
  const int tstart = w ? h0 : 0;
  const int tend   = w ? ntile : h0;
  const float gam = (wsf + WS_GAM)[bh & (NHEAD-1)];
  const float aq = AqF[(size_t)bh*SEQ + i];

  for (int idx = tid; idx < SEQ; idx += 128) s_bk[idx] = BkF[(size_t)bh*SEQ + idx];

  // Q fragments (B-operand): [part][ks][hi/lo]
  bf16x8 qf[8];
  {
    const unsigned short* qb[4] = {qmh, qml, sch, scl};
#pragma unroll
    for (int part = 0; part < 2; ++part)
#pragma unroll
      for (int hl = 0; hl < 2; ++hl)
#pragma unroll
        for (int ks = 0; ks < 2; ++ks)
          qf[part*4 + ks*2 + hl] =
            *(const bf16x8*)(qb[part*2+hl] + ((size_t)bh*SEQ + i)*DK + ks*32 + lg*8);
  }
  __syncthreads();

  // score: K is bf16-hi only; Q carries hi/lo (2-term)
  auto score_tile = [&](int t, float* s) {
    const int j0 = t*16;
    f32x4 accA = {0.f,0.f,0.f,0.f};
    f32x4 accB = {0.f,0.f,0.f,0.f};
    const size_t krow = ((size_t)bh*SEQ + j0 + li)*DK + lg*8;
#pragma unroll
    for (int part = 0; part < 2; ++part) {
      const unsigned short* khp = part ? skh : kmh;
#pragma unroll
      for (int ks = 0; ks < 2; ++ks) {
        bf16x8 kh = *(const bf16x8*)(khp + krow + ks*32);
        accA = MFMA32(kh, qf[part*4+ks*2+0], accA);
        accB = MFMA32(kh, qf[part*4+ks*2+1], accB);
      }
    }
    const float4 bk4 = *(const float4*)&s_bk[j0 + lg*4];
    float bks[4] = {bk4.x, bk4.y, bk4.z, bk4.w};
#pragma unroll
    for (int r = 0; r < 4; ++r) {
      int j = j0 + lg*4 + r;
      float v = (accA[r] + accB[r]) - aq - bks[r];
      s[r] = (j > i) ? -3.0e38f : v;
    }
  };

  // ---- pass 1: local softmax-1 stats over this wave's range ----
  float m1 = -3.0e38f, tot = 0.f;
  for (int t = tstart; t < tend; ++t) {
    float s[4]; score_tile(t, s);
    float tm = fmaxf(fmaxf(s[0], s[1]), fmaxf(s[2], s[3]));
    tm = fmaxf(tm, __shfl_xor(tm, 16));
    tm = fmaxf(tm, __shfl_xor(tm, 32));
    float m1n = fmaxf(m1, tm);
    float lsum = __expf(s[0]-m1n) + __expf(s[1]-m1n) + __expf(s[2]-m1n) + __expf(s[3]-m1n);
    lsum += __shfl_xor(lsum, 16); lsum += __shfl_xor(lsum, 32);
    tot = tot * __expf(m1 - m1n) + lsum;
    m1 = m1n;
  }
  // ---- merge pass-1 stats across the two waves ----
  if (lg == 0) { s_ex[w][0][li] = m1; s_ex[w][1][li] = tot; }
  __syncthreads();
  float run;
  {
    float m0 = s_ex[0][0][li], t0 = s_ex[0][1][li];
    float m1b = s_ex[1][0][li], t1 = s_ex[1][1][li];
    float mg = fmaxf(m0, m1b);
    float e0 = __expf(m0 - mg), e1 = __expf(m1b - mg);
    tot = t0*e0 + t1*e1;
    run = w ? t0*e0 : 0.f;    // mass preceding this wave's range
    m1 = mg;
  }
  const float invtot = 1.0f / tot;

  // ---- pass 2: scan + online softmax-2 + PV over this wave's range ----
  f32x4 accm[4], accc[4];
  {
    f32x4 z = {0.f,0.f,0.f,0.f};
#pragma unroll
    for (int dt = 0; dt < 4; ++dt) { accm[dt] = z; accc[dt] = z; }
  }
  float m2 = -3.0e38f, sum2 = 0.f;

  auto scan_tile = [&](int t, float* s2) {
    float s[4]; score_tile(t, s);
    float e0 = __expf(s[0]-m1), e1 = __expf(s[1]-m1),
          e2 = __expf(s[2]-m1), e3 = __expf(s[3]-m1);
    float p0 = e0, p1 = p0+e1, p2 = p1+e2, p3 = p2+e3;
    float lt = p3;
    float a = __shfl_up(lt, 16), b = __shfl_up(lt, 32), c = __shfl_up(lt, 48);
    float excl = (lg >= 1 ? a : 0.f) + (lg >= 2 ? b : 0.f) + (lg >= 3 ? c : 0.f);
    float base = run + excl;
    float cums[4] = {base+p0, base+p1, base+p2, base+p3};
    float ttr = lt;
    ttr += __shfl_xor(ttr, 16); ttr += __shfl_xor(ttr, 32);
    run += ttr;
#pragma unroll
    for (int r = 0; r < 4; ++r) {
      int j = t*16 + lg*4 + r;
      float rem = fmaxf(tot - cums[r], 0.f) * invtot;
      float pos = fmaxf((float)(i - j), 0.f);
      float dist = sqrtf(rem * pos);
      float eff = fmaxf(__expf(dist * gam), 1e-5f);
      s2[r] = (j > i) ? -3.0e38f : s[r] * eff;
    }
  };

  for (int t0 = tstart; t0 < tend; t0 += 2) {
    float s2A[4], s2B[4];
    scan_tile(t0, s2A);
    const bool hasB = (t0 + 1) < tend;
    if (hasB) scan_tile(t0+1, s2B);
    else { s2B[0]=s2B[1]=s2B[2]=s2B[3] = -3.0e38f; }
    float mt = fmaxf(fmaxf(fmaxf(s2A[0],s2A[1]), fmaxf(s2A[2],s2A[3])),
                     fmaxf(fmaxf(s2B[0],s2B[1]), fmaxf(s2B[2],s2B[3])));
    mt = fmaxf(mt, __shfl_xor(mt, 16));
    mt = fmaxf(mt, __shfl_xor(mt, 32));
    float m2n = fmaxf(m2, mt);
    float scale = __expf(m2 - m2n);
    float scale2 = scale * scale;
#pragma unroll
    for (int dt = 0; dt < 4; ++dt) { accm[dt] *= scale; accc[dt] *= scale2; }
    float pA[4], pB[4];
#pragma unroll
    for (int r = 0; r < 4; ++r) { pA[r] = __expf(s2A[r]-m2n); pB[r] = __expf(s2B[r]-m2n); }
    float ps = pA[0]+pA[1]+pA[2]+pA[3] + pB[0]+pB[1]+pB[2]+pB[3];
    ps += __shfl_xor(ps, 16); ps += __shfl_xor(ps, 32);
    sum2 = sum2 * scale + ps;
    m2 = m2n;
    bf16x8 pbm, pbc;
#pragma unroll
    for (int r = 0; r < 4; ++r) {
      pbm[r]   = (short)f2bf(pA[r]);
      pbm[4+r] = (short)f2bf(pB[r]);
      pbc[r]   = (short)f2bf(pA[r]*pA[r]);
      pbc[4+r] = (short)f2bf(pB[r]*pB[r]);
    }
    const int j0A = t0*16;
    const int j0B = hasB ? j0A + 16 : j0A;
    union V16 { struct { uint2 lo, hi; } u; bf16x8 v; };
#pragma unroll
    for (int dt = 0; dt < 4; ++dt) {
      const size_t vrow = ((size_t)bh*DK + dt*16 + li)*SEQ;
      V16 vm_, vc_;
      vm_.u.lo = *(const uint2*)(vmT + vrow + j0A + lg*4);
      vm_.u.hi = *(const uint2*)(vmT + vrow + j0B + lg*4);
      vc_.u.lo = *(const uint2*)(vcT + vrow + j0A + lg*4);
      vc_.u.hi = *(const uint2*)(vcT + vrow + j0B + lg*4);
      accm[dt] = MFMA32(vm_.v, pbm, accm[dt]);
      accc[dt] = MFMA32(vc_.v, pbc, accc[dt]);
    }
  }

  // ---- merge the two waves' PV state, wave0 stores ----
  __syncthreads();                       // s_ex reuse
  if (lg == 0) s_ex[w][0][li] = m2;
  __syncthreads();
  const float m2g = fmaxf(s_ex[0][0][li], s_ex[1][0][li]);
  const float sc = __expf(m2 - m2g);
  const float sc2 = sc * sc;
  if (w == 1) {
#pragma unroll
    for (int dt = 0; dt < 4; ++dt)
#pragma unroll
      for (int reg = 0; reg < 4; ++reg) {
        s_acc[l][dt*4 + reg]      = accm[dt][reg] * sc;
        s_acc[l][16 + dt*4 + reg] = accc[dt][reg] * sc2;
      }
    if (lg == 0) s_ex[1][1][li] = sum2 * sc;
  }
  __syncthreads();
  if (w == 0) {
    const float sum2g = sum2 * sc + s_ex[1][1][li];
    const float inv2 = 1.0f / sum2g;
    const float inv2c = inv2 * inv2;
    const bool zero = (i == 0);
    float* om_p = omF + ((size_t)bh*SEQ + i)*DK;
    float* oc_p = ocF + ((size_t)bh*SEQ + i)*DK;
#pragma unroll
    for (int dt = 0; dt < 4; ++dt) {
      float4 vm4, vc4;
      vm4.x = (accm[dt][0]*sc + s_acc[l][dt*4+0]) * inv2;
      vm4.y = (accm[dt][1]*sc + s_acc[l][dt*4+1]) * inv2;
      vm4.z = (accm[dt][2]*sc + s_acc[l][dt*4+2]) * inv2;
      vm4.w = (accm[dt][3]*sc + s_acc[l][dt*4+3]) * inv2;
      vc4.x = (accc[dt][0]*sc2 + s_acc[l][16+dt*4+0]) * inv2c;
      vc4.y = (accc[dt][1]*sc2 + s_acc[l][16+dt*4+1]) * inv2c;
      vc4.z = (accc[dt][2]*sc2 + s_acc[l][16+dt*4+2]) * inv2c;
      vc4.w = (accc[dt][3]*sc2 + s_acc[l][16+dt*4+3]) * inv2c;
      if (zero) { vm4 = make_float4(0.f,0.f,0.f,0.f); vc4 = vm4; }
      *(float4*)(om_p + dt*16 + lg*4) = vm4;
      *(float4*)(oc_p + dt*16 + lg*4) = vc4;
    }
  }
}

// ---------------- output GEMM: d_out[m][n] = sum_k OM[m,k] * Wo[n][k] ----------------
__global__ __launch_bounds__(256) void k_outM(float* wsf,
                                              const float* w_mean, const float* w_cov,
                                              float* outp)
{
  __shared__ __align__(16) unsigned short Ah[4096];
  __shared__ __align__(16) unsigned short Al[4096];
  __shared__ __align__(16) unsigned short Bh[4096];
  __shared__ __align__(16) unsigned short Bl[4096];
  const int y = blockIdx.y;
  const float* A = wsf + (y ? WS_OC : WS_OM);
  const float* W = y ? w_cov : w_mean;
  float* out = outp + (size_t)y * 4194304ull;

  const int tid = threadIdx.x;
  const int l = tid & 63, li = l & 15, lg = l >> 4;
  const int w = tid >> 6, wr = w >> 1, wc = w & 1;
  const int m0 = (blockIdx.x >> 2) * 128;
  const int n0 = (blockIdx.x & 3) * 128;
  const int r0 = tid >> 2, c0 = tid & 3, r1 = r0 + 64;
  const int wo0 = r0*64 + ((c0 ^ ((r0>>1)&3))*16);
  const int wo1 = r1*64 + ((c0 ^ ((r1>>1)&3))*16);
  int roA[4], roB[4];
#pragma unroll
  for (int mi = 0; mi < 4; ++mi) {
    int r  = wr*64 + mi*16 + li;
    roA[mi] = r*64 + ((lg ^ ((r>>1)&3))*16);
    int rn = wc*64 + mi*16 + li;
    roB[mi] = rn*64 + ((lg ^ ((rn>>1)&3))*16);
  }
  const int mA0 = m0 + r0, mA1 = m0 + r1;
  const size_t abase0 = ((size_t)(mA0 >> 9) * NHEAD * SEQ + (mA0 & 511)) * DK;
  const size_t abase1 = ((size_t)(mA1 >> 9) * NHEAD * SEQ + (mA1 & 511)) * DK;
  const float* wp0 = W + (size_t)(n0 + r0)*DMODEL + c0*8;
  const float* wp1 = W + (size_t)(n0 + r1)*DMODEL + c0*8;

  auto aload = [&](size_t abase, int k, float* t8) {
    const float* p = A + abase + (size_t)(k >> 6) * (SEQ*DK) + (k & 63);
    ld8_f32(p, t8);
  };

  uint4 a0h,a0l,a1h,a1l,b0h,b0l,b1h,b1l;
  {
    float t8[8];
    int k0 = c0*8;
    aload(abase0, k0, t8); cvt8(t8, a0h, a0l);
    aload(abase1, k0, t8); cvt8(t8, a1h, a1l);
    ld8_f32(wp0, t8); cvt8(t8, b0h, b0l);
    ld8_f32(wp1, t8); cvt8(t8, b1h, b1l);
  }
  f32x4 acc[4][4];
  f32x4 z = {0.f,0.f,0.f,0.f};
#pragma unroll
  for (int a = 0; a < 4; ++a)
#pragma unroll
    for (int b = 0; b < 4; ++b) acc[a][b] = z;

  for (int kt = 0; kt < DMODEL; kt += 32) {
    __syncthreads();
    *(uint4*)((char*)Ah + wo0) = a0h; *(uint4*)((char*)Al + wo0) = a0l;
    *(uint4*)((char*)Ah + wo1) = a1h; *(uint4*)((char*)Al + wo1) = a1l;
    *(uint4*)((char*)Bh + wo0) = b0h; *(uint4*)((char*)Bl + wo0) = b0l;
    *(uint4*)((char*)Bh + wo1) = b1h; *(uint4*)((char*)Bl + wo1) = b1l;
    __syncthreads();
    if (kt + 32 < DMODEL) {
      float t8[8];
      int kn = kt + 32 + c0*8;
      aload(abase0, kn, t8); cvt8(t8, a0h, a0l);
      aload(abase1, kn, t8); cvt8(t8, a1h, a1l);
      ld8_f32(wp0 + kt + 32, t8); cvt8(t8, b0h, b0l);
      ld8_f32(wp1 + kt + 32, t8); cvt8(t8, b1h, b1l);
    }
    bf16x8 ah[4], alo[4], bh[4], blo[4];
#pragma unroll
    for (int mi = 0; mi < 4; ++mi) {
      ah[mi]  = *(const bf16x8*)((const char*)Ah + roA[mi]);
      alo[mi] = *(const bf16x8*)((const char*)Al + roA[mi]);
      bh[mi]  = *(const bf16x8*)((const char*)Bh + roB[mi]);
      blo[mi] = *(const bf16x8*)((const char*)Bl + roB[mi]);
    }
#pragma unroll
    for (int mi = 0; mi < 4; ++mi)
#pragma unroll
      for (int nj = 0; nj < 4; ++nj) {
        acc[mi][nj] = MFMA32(ah[mi],  bh[nj],  acc[mi][nj]);
        acc[mi][nj] = MFMA32(alo[mi], bh[nj],  acc[mi][nj]);
        acc[mi][nj] = MFMA32(ah[mi],  blo[nj], acc[mi][nj]);
      }
  }
#pragma unroll
  for (int mi = 0; mi < 4; ++mi)
#pragma unroll
    for (int nj = 0; nj < 4; ++nj)
#pragma unroll
      for (int reg = 0; reg < 4; ++reg) {
        int m = m0 + wr*64 + mi*16 + 4*lg + reg;
        int n = n0 + wc*64 + nj*16 + li;
        out[(size_t)m*DMODEL + n] = acc[mi][nj][reg];
      }
}

extern "C" void kernel_launch(void* const* d_in, const int* in_sizes, int n_in,
                              void* d_out, int out_size, void* d_ws, size_t ws_size,
                              hipStream_t stream) {
  (void)in_sizes; (void)n_in; (void)out_size; (void)ws_size;
  float* wsf = (float*)d_ws;

  k_gamma<<<1, 64, 0, stream>>>((const float*)d_in[14], wsf);
  k_projM<<<dim3(256, 6), 256, 0, stream>>>(
      (const float*)d_in[0], (const float*)d_in[1],
      (const float*)d_in[2], (const float*)d_in[3],
      (const float*)d_in[4], (const float*)d_in[5],
      (const float*)d_in[6], (const float*)d_in[7],
      (const float*)d_in[8], (const float*)d_in[9],
      (const float*)d_in[10], (const float*)d_in[11],
      wsf);
  k_sumAB<<<256, 256, 0, stream>>>(wsf);
  k_attn2<<<4096, 128, 0, stream>>>(wsf);
  k_outM<<<dim3(256, 2), 256, 0, stream>>>(wsf, (const float*)d_in[12],
                                           (const float*)d_in[13], (float*)d_out);
}

// Round 9
// 243.600 us; speedup vs baseline: 5.2260x; 1.2559x over previous
//
#include <hip/hip_runtime.h>
#include <hip/hip_bf16.h>

#define SEQ    512
#define DMODEL 512
#define NHEAD  8
#define DK     64
#define BS     16
#define NBH    (BS*NHEAD)       // 128
#define HSZ    (SEQ*DK)         // 32768 per (b,h)

typedef __attribute__((ext_vector_type(8))) short bf16x8;
typedef __attribute__((ext_vector_type(4))) float f32x4;

#define MFMA32(A,B,C) __builtin_amdgcn_mfma_f32_16x16x32_bf16(A,B,C,0,0,0)

// ---------------- workspace layout (fp32 units) ----------------
#define WS_GAM 16ull
#define WS_AQM 256ull
#define WS_AQC (WS_AQM +  65536ull)
#define WS_BKM (WS_AQM + 131072ull)
#define WS_BKC (WS_AQM + 196608ull)
#define WS_AQF (WS_AQM + 262144ull)
#define WS_BKF (WS_AQM + 327680ull)
#define WS_OM  1048576ull
#define WS_OC  (WS_OM + 4194304ull)
#define WS_BF  (WS_OC + 4194304ull)     // bf16 arrays region
#define ARRE   4194304ull               // elems per bf16 array
// bf16 array ids
#define A_QMH 0
#define A_QML 1
#define A_SCH 2
#define A_SCL 3
#define A_KMH 4
#define A_SKH 6
#define A_VMT 8
#define A_VCT 9

__device__ __forceinline__ unsigned short* warr(float* wsf, int idx) {
  return (unsigned short*)(wsf + WS_BF) + (size_t)idx * ARRE;
}

// ---------- helpers ----------
__device__ __forceinline__ float bf2f(unsigned short h) {
  union { float f; unsigned u; } v; v.u = ((unsigned)h) << 16; return v.f;
}
__device__ __forceinline__ unsigned short f2bf(float f) {
  union { float f; unsigned u; } v; v.f = f;
  unsigned u = v.u;
  u += 0x7FFFu + ((u >> 16) & 1u);   // RNE
  return (unsigned short)(u >> 16);
}
__device__ __forceinline__ void ld8_f32(const float* p, float* v) {
  float4 a = *(const float4*)p; float4 b = *(const float4*)(p+4);
  v[0]=a.x;v[1]=a.y;v[2]=a.z;v[3]=a.w;v[4]=b.x;v[5]=b.y;v[6]=b.z;v[7]=b.w;
}
// pack 2 fp32 -> [bf16(a) | bf16(b)<<16], round-half-up, via v_perm
__device__ __forceinline__ unsigned pk2bf(float a, float b) {
  union { float f; unsigned u; } x, y;
  x.f = a; y.f = b;
  return __builtin_amdgcn_perm(y.u + 0x8000u, x.u + 0x8000u, 0x07060302u);
}
// 8 regs fp32 -> packed bf16 uint4 (round-half-up)
__device__ __forceinline__ uint4 cvt8r(const float* t8) {
  uint4 h;
  h.x = pk2bf(t8[0], t8[1]);
  h.y = pk2bf(t8[2], t8[3]);
  h.z = pk2bf(t8[4], t8[5]);
  h.w = pk2bf(t8[6], t8[7]);
  return h;
}
__device__ __forceinline__ uint4 cvt8h(const float* p) {
  float t8[8]; ld8_f32(p, t8); return cvt8r(t8);
}

__global__ void k_gamma(const float* __restrict__ g_in, float* __restrict__ wsf) {
  int t = threadIdx.x;
  if (t >= NHEAD) return;
  float g = g_in[t];
  float sp = (g > 20.f) ? g : log1pf(expf(g));
  (wsf + WS_GAM)[t] = -sp;
}

// ---------------- projections: 1-term bf16 MFMA (consistent rounding) ----------------
// y: 0 qm, 1 km, 2 qc, 3 kc, 4 vm, 5 vc
__global__ __launch_bounds__(256) void k_projM(
    const float* xqm, const float* xqc, const float* xkm, const float* xkc,
    const float* xvm, const float* xvc,
    const float* wqm, const float* wqc, const float* wkm, const float* wkc,
    const float* wvm, const float* wvc,
    float* wsf)
{
  __shared__ __align__(16) unsigned short Ah[4096];
  __shared__ __align__(16) unsigned short Bh[4096];
  const int y = blockIdx.y;
  const float* X; const float* W;
  unsigned short *outh = nullptr, *outl = nullptr;
  float* sums = nullptr;
  float qscale = 1.0f; int mode = 0;  // 0 mean, 1 cov, 2 v
  switch (y) {
    case 0: X=xqm; W=wqm; outh=warr(wsf,A_QMH); outl=warr(wsf,A_QML); sums=wsf+WS_AQM; qscale=0.25f; mode=0; break;
    case 1: X=xkm; W=wkm; outh=warr(wsf,A_KMH); outl=nullptr;         sums=wsf+WS_BKM; qscale=1.0f;  mode=0; break;
    case 2: X=xqc; W=wqc; outh=warr(wsf,A_SCH); outl=warr(wsf,A_SCL); sums=wsf+WS_AQC; qscale=0.25f; mode=1; break;
    case 3: X=xkc; W=wkc; outh=warr(wsf,A_SKH); outl=nullptr;         sums=wsf+WS_BKC; qscale=1.0f;  mode=1; break;
    case 4: X=xvm; W=wvm; outh=warr(wsf,A_VMT); mode=2; break;
    default:X=xvc; W=wvc; outh=warr(wsf,A_VCT); mode=2; break;
  }
  const int tid = threadIdx.x;
  const int l = tid & 63, li = l & 15, lg = l >> 4;
  const int w = tid >> 6, wr = w >> 1, wc = w & 1;
  // XCD-affine swizzle: each XCD owns 8 m-tiles (X read once per XCD)
  const int blk = blockIdx.x;
  const int xcd = blk & 7, qq = blk >> 3;           // qq 0..31
  const int m0 = (xcd*8 + (qq & 7)) * 128;
  const int n0 = (qq >> 3) * 128;
  const int r0 = tid >> 2, c0 = tid & 3, r1 = r0 + 64;
  const int wo0 = r0*64 + ((c0 ^ ((r0>>1)&3))*16);
  const int wo1 = r1*64 + ((c0 ^ ((r1>>1)&3))*16);
  int roA[4], roB[4];
#pragma unroll
  for (int mi = 0; mi < 4; ++mi) {
    int r  = wr*64 + mi*16 + li;
    roA[mi] = r*64 + ((lg ^ ((r>>1)&3))*16);
    int rn = wc*64 + mi*16 + li;
    roB[mi] = rn*64 + ((lg ^ ((rn>>1)&3))*16);
  }
  const float* xp0 = X + (size_t)(m0+r0)*DMODEL + c0*8;
  const float* xp1 = X + (size_t)(m0+r1)*DMODEL + c0*8;
  const float* wp0 = W + (size_t)(n0+r0)*DMODEL + c0*8;
  const float* wp1 = W + (size_t)(n0+r1)*DMODEL + c0*8;
  uint4 a0 = cvt8h(xp0);
  uint4 a1 = cvt8h(xp1);
  uint4 b0 = cvt8h(wp0);
  uint4 b1 = cvt8h(wp1);

  f32x4 acc[4][4];
  f32x4 z = {0.f,0.f,0.f,0.f};
#pragma unroll
  for (int a = 0; a < 4; ++a)
#pragma unroll
    for (int b = 0; b < 4; ++b) acc[a][b] = z;

  for (int kt = 0; kt < DMODEL; kt += 32) {
    __syncthreads();
    *(uint4*)((char*)Ah + wo0) = a0;
    *(uint4*)((char*)Ah + wo1) = a1;
    *(uint4*)((char*)Bh + wo0) = b0;
    *(uint4*)((char*)Bh + wo1) = b1;
    __syncthreads();
    if (kt + 32 < DMODEL) {
      a0 = cvt8h(xp0 + kt + 32);
      a1 = cvt8h(xp1 + kt + 32);
      b0 = cvt8h(wp0 + kt + 32);
      b1 = cvt8h(wp1 + kt + 32);
    }
    bf16x8 ah[4], bh[4];
#pragma unroll
    for (int mi = 0; mi < 4; ++mi) {
      ah[mi] = *(const bf16x8*)((const char*)Ah + roA[mi]);
      bh[mi] = *(const bf16x8*)((const char*)Bh + roB[mi]);
    }
#pragma unroll
    for (int mi = 0; mi < 4; ++mi)
#pragma unroll
      for (int nj = 0; nj < 4; ++nj)
        acc[mi][nj] = MFMA32(ah[mi], bh[nj], acc[mi][nj]);
  }

  const int head = ((n0 >> 6) + wc);
  if (mode <= 1) {
    const bool kside = (outl == nullptr);
#pragma unroll
    for (int mi = 0; mi < 4; ++mi)
#pragma unroll
      for (int reg = 0; reg < 4; ++reg) {
        float rs = 0.f;
#pragma unroll
        for (int nj = 0; nj < 4; ++nj) {
          float v = acc[mi][nj][reg];
          if (mode == 0) {
            float vs = (kside) ? bf2f(f2bf(v)) : v;   // consistent with stored K
            rs += vs*vs;
          } else {
            rs += v;                                   // raw cov sum (reference semantics)
          }
        }
        rs += __shfl_xor(rs, 1); rs += __shfl_xor(rs, 2);
        rs += __shfl_xor(rs, 4); rs += __shfl_xor(rs, 8);
        if (li == 0) {
          int m = m0 + wr*64 + mi*16 + 4*lg + reg;
          sums[((size_t)(m >> 9)*NHEAD + head)*SEQ + (m & 511)] = rs;
        }
      }
#pragma unroll
    for (int mi = 0; mi < 4; ++mi)
#pragma unroll
      for (int nj = 0; nj < 4; ++nj)
#pragma unroll
        for (int reg = 0; reg < 4; ++reg) {
          float v = acc[mi][nj][reg];
          if (mode == 1) v = sqrtf(fmaxf(v, 1e-24f));
          v *= qscale;
          unsigned short h16 = f2bf(v);
          int m = m0 + wr*64 + mi*16 + 4*lg + reg;
          int n = n0 + wc*64 + nj*16 + li;
          size_t dst = ((size_t)((m >> 9)*NHEAD + (n >> 6))*SEQ + (m & 511))*DK + (n & 63);
          outh[dst] = h16;
          if (outl) outl[dst] = f2bf(v - bf2f(h16));
        }
  } else {
    // V: transposed [bh][d][s], 4 consecutive s per store
#pragma unroll
    for (int mi = 0; mi < 4; ++mi)
#pragma unroll
      for (int nj = 0; nj < 4; ++nj) {
        int mb = m0 + wr*64 + mi*16 + 4*lg;
        int n = n0 + wc*64 + nj*16 + li;
        int b = mb >> 9, s = mb & 511, d = n & 63;
        unsigned e0 = f2bf(acc[mi][nj][0]);
        unsigned e1 = f2bf(acc[mi][nj][1]);
        unsigned e2 = f2bf(acc[mi][nj][2]);
        unsigned e3 = f2bf(acc[mi][nj][3]);
        uint2 pk; pk.x = e0 | (e1 << 16); pk.y = e2 | (e3 << 16);
        *(uint2*)(outh + ((size_t)(b*NHEAD + head)*DK + d)*SEQ + s) = pk;
      }
  }
}

__global__ void k_sumAB(float* wsf) {
  int i = blockIdx.x * 256 + threadIdx.x;
  if (i < NBH*SEQ) {
    (wsf+WS_AQF)[i] = 0.125f * ((wsf+WS_AQM)[i] + (wsf+WS_AQC)[i]);
    (wsf+WS_BKF)[i] = 0.125f * ((wsf+WS_BKM)[i] + (wsf+WS_BKC)[i]);
  }
}

// ---------------- flash-style fused attention, split-j ----------------
__global__ __launch_bounds__(128) void k_attn2(float* wsf)
{
  __shared__ float s_bk[SEQ];
  __shared__ float s_ex[2][2][16];
  __shared__ __align__(16) float s_acc[64][33];

  const unsigned short* qmh = warr(wsf, A_QMH);
  const unsigned short* qml = warr(wsf, A_QML);
  const unsigned short* sch = warr(wsf, A_SCH);
  const unsigned short* scl = warr(wsf, A_SCL);
  const unsigned short* kmh = warr(wsf, A_KMH);
  const unsigned short* skh = warr(wsf, A_SKH);
  const unsigned short* vmT = warr(wsf, A_VMT);
  const unsigned short* vcT = warr(wsf, A_VCT);
  float* omF = wsf + WS_OM;
  float* ocF = wsf + WS_OC;
  const float* AqF = wsf + WS_AQF;
  const float* BkF = wsf + WS_BKF;

  const int tid = threadIdx.x;
  const int l = tid & 63, li = l & 15, lg = l >> 4;
  const int w = tid >> 6;                    // 0..1
  const int blk = blockIdx.x;                // 0..4095
  const int xcd = blk & 7;
  const int q   = blk >> 3;                  // 0..511
  const int bh  = xcd*16 + (q & 15);
  const int rt  = 31 - (q >> 4);             // row-tile 0..31, heavy first
  const int i = rt*16 + li;
  const int ntile = rt + 1;
  const int h0 = (ntile + 1) >> 1;
  const int tstart = w ? h0 : 0;
  const int tend   = w ? ntile : h0;
  const float gam = (wsf + WS_GAM)[bh & (NHEAD-1)];
  const float aq = AqF[(size_t)bh*SEQ + i];

  for (int idx = tid; idx < SEQ; idx += 128) s_bk[idx] = BkF[(size_t)bh*SEQ + idx];

  bf16x8 qf[8];
  {
    const unsigned short* qb[4] = {qmh, qml, sch, scl};
#pragma unroll
    for (int part = 0; part < 2; ++part)
#pragma unroll
      for (int hl = 0; hl < 2; ++hl)
#pragma unroll
        for (int ks = 0; ks < 2; ++ks)
          qf[part*4 + ks*2 + hl] =
            *(const bf16x8*)(qb[part*2+hl] + ((size_t)bh*SEQ + i)*DK + ks*32 + lg*8);
  }
  __syncthreads();

  auto score_tile = [&](int t, float* s) {
    const int j0 = t*16;
    f32x4 accA = {0.f,0.f,0.f,0.f};
    f32x4 accB = {0.f,0.f,0.f,0.f};
    const size_t krow = ((size_t)bh*SEQ + j0 + li)*DK + lg*8;
#pragma unroll
    for (int part = 0; part < 2; ++part) {
      const unsigned short* khp = part ? skh : kmh;
#pragma unroll
      for (int ks = 0; ks < 2; ++ks) {
        bf16x8 kh = *(const bf16x8*)(khp + krow + ks*32);
        accA = MFMA32(kh, qf[part*4+ks*2+0], accA);
        accB = MFMA32(kh, qf[part*4+ks*2+1], accB);
      }
    }
    const float4 bk4 = *(const float4*)&s_bk[j0 + lg*4];
    float bks[4] = {bk4.x, bk4.y, bk4.z, bk4.w};
#pragma unroll
    for (int r = 0; r < 4; ++r) {
      int j = j0 + lg*4 + r;
      float v = (accA[r] + accB[r]) - aq - bks[r];
      s[r] = (j > i) ? -3.0e38f : v;
    }
  };

  // ---- pass 1 ----
  float m1 = -3.0e38f, tot = 0.f;
  for (int t = tstart; t < tend; ++t) {
    float s[4]; score_tile(t, s);
    float tm = fmaxf(fmaxf(s[0], s[1]), fmaxf(s[2], s[3]));
    tm = fmaxf(tm, __shfl_xor(tm, 16));
    tm = fmaxf(tm, __shfl_xor(tm, 32));
    float m1n = fmaxf(m1, tm);
    float lsum = __expf(s[0]-m1n) + __expf(s[1]-m1n) + __expf(s[2]-m1n) + __expf(s[3]-m1n);
    lsum += __shfl_xor(lsum, 16); lsum += __shfl_xor(lsum, 32);
    tot = tot * __expf(m1 - m1n) + lsum;
    m1 = m1n;
  }
  if (lg == 0) { s_ex[w][0][li] = m1; s_ex[w][1][li] = tot; }
  __syncthreads();
  float run;
  {
    float m0 = s_ex[0][0][li], t0 = s_ex[0][1][li];
    float m1b = s_ex[1][0][li], t1 = s_ex[1][1][li];
    float mg = fmaxf(m0, m1b);
    float e0 = __expf(m0 - mg), e1 = __expf(m1b - mg);
    tot = t0*e0 + t1*e1;
    run = w ? t0*e0 : 0.f;
    m1 = mg;
  }
  const float invtot = 1.0f / tot;

  // ---- pass 2 ----
  f32x4 accm[4], accc[4];
  {
    f32x4 z = {0.f,0.f,0.f,0.f};
#pragma unroll
    for (int dt = 0; dt < 4; ++dt) { accm[dt] = z; accc[dt] = z; }
  }
  float m2 = -3.0e38f, sum2 = 0.f;

  auto scan_tile = [&](int t, float* s2) {
    float s[4]; score_tile(t, s);
    float e0 = __expf(s[0]-m1), e1 = __expf(s[1]-m1),
          e2 = __expf(s[2]-m1), e3 = __expf(s[3]-m1);
    float p0 = e0, p1 = p0+e1, p2 = p1+e2, p3 = p2+e3;
    float lt = p3;
    float a = __shfl_up(lt, 16), b = __shfl_up(lt, 32), c = __shfl_up(lt, 48);
    float excl = (lg >= 1 ? a : 0.f) + (lg >= 2 ? b : 0.f) + (lg >= 3 ? c : 0.f);
    float base = run + excl;
    float cums[4] = {base+p0, base+p1, base+p2, base+p3};
    float ttr = lt;
    ttr += __shfl_xor(ttr, 16); ttr += __shfl_xor(ttr, 32);
    run += ttr;
#pragma unroll
    for (int r = 0; r < 4; ++r) {
      int j = t*16 + lg*4 + r;
      float rem = fmaxf(tot - cums[r], 0.f) * invtot;
      float pos = fmaxf((float)(i - j), 0.f);
      float dist = sqrtf(rem * pos);
      float eff = fmaxf(__expf(dist * gam), 1e-5f);
      s2[r] = (j > i) ? -3.0e38f : s[r] * eff;
    }
  };

  for (int t0 = tstart; t0 < tend; t0 += 2) {
    float s2A[4], s2B[4];
    scan_tile(t0, s2A);
    const bool hasB = (t0 + 1) < tend;
    if (hasB) scan_tile(t0+1, s2B);
    else { s2B[0]=s2B[1]=s2B[2]=s2B[3] = -3.0e38f; }
    float mt = fmaxf(fmaxf(fmaxf(s2A[0],s2A[1]), fmaxf(s2A[2],s2A[3])),
                     fmaxf(fmaxf(s2B[0],s2B[1]), fmaxf(s2B[2],s2B[3])));
    mt = fmaxf(mt, __shfl_xor(mt, 16));
    mt = fmaxf(mt, __shfl_xor(mt, 32));
    float m2n = fmaxf(m2, mt);
    float scale = __expf(m2 - m2n);
    float scale2 = scale * scale;
#pragma unroll
    for (int dt = 0; dt < 4; ++dt) { accm[dt] *= scale; accc[dt] *= scale2; }
    float pA[4], pB[4];
#pragma unroll
    for (int r = 0; r < 4; ++r) { pA[r] = __expf(s2A[r]-m2n); pB[r] = __expf(s2B[r]-m2n); }
    float ps = pA[0]+pA[1]+pA[2]+pA[3] + pB[0]+pB[1]+pB[2]+pB[3];
    ps += __shfl_xor(ps, 16); ps += __shfl_xor(ps, 32);
    sum2 = sum2 * scale + ps;
    m2 = m2n;
    union PU { uint4 u; bf16x8 v; } pm, pc;
    pm.u.x = pk2bf(pA[0], pA[1]); pm.u.y = pk2bf(pA[2], pA[3]);
    pm.u.z = pk2bf(pB[0], pB[1]); pm.u.w = pk2bf(pB[2], pB[3]);
    pc.u.x = pk2bf(pA[0]*pA[0], pA[1]*pA[1]); pc.u.y = pk2bf(pA[2]*pA[2], pA[3]*pA[3]);
    pc.u.z = pk2bf(pB[0]*pB[0], pB[1]*pB[1]); pc.u.w = pk2bf(pB[2]*pB[2], pB[3]*pB[3]);
    const int j0A = t0*16;
    const int j0B = hasB ? j0A + 16 : j0A;
    union V16 { struct { uint2 lo, hi; } u; bf16x8 v; };
#pragma unroll
    for (int dt = 0; dt < 4; ++dt) {
      const size_t vrow = ((size_t)bh*DK + dt*16 + li)*SEQ;
      V16 vm_, vc_;
      vm_.u.lo = *(const uint2*)(vmT + vrow + j0A + lg*4);
      vm_.u.hi = *(const uint2*)(vmT + vrow + j0B + lg*4);
      vc_.u.lo = *(const uint2*)(vcT + vrow + j0A + lg*4);
      vc_.u.hi = *(const uint2*)(vcT + vrow + j0B + lg*4);
      accm[dt] = MFMA32(vm_.v, pm.v, accm[dt]);
      accc[dt] = MFMA32(vc_.v, pc.v, accc[dt]);
    }
  }

  // ---- merge + store ----
  __syncthreads();
  if (lg == 0) s_ex[w][0][li] = m2;
  __syncthreads();
  const float m2g = fmaxf(s_ex[0][0][li], s_ex[1][0][li]);
  const float sc = __expf(m2 - m2g);
  const float sc2 = sc * sc;
  if (w == 1) {
#pragma unroll
    for (int dt = 0; dt < 4; ++dt)
#pragma unroll
      for (int reg = 0; reg < 4; ++reg) {
        s_acc[l][dt*4 + reg]      = accm[dt][reg] * sc;
        s_acc[l][16 + dt*4 + reg] = accc[dt][reg] * sc2;
      }
    if (lg == 0) s_ex[1][1][li] = sum2 * sc;
  }
  __syncthreads();
  if (w == 0) {
    const float sum2g = sum2 * sc + s_ex[1][1][li];
    const float inv2 = 1.0f / sum2g;
    const float inv2c = inv2 * inv2;
    const bool zero = (i == 0);
    float* om_p = omF + ((size_t)bh*SEQ + i)*DK;
    float* oc_p = ocF + ((size_t)bh*SEQ + i)*DK;
#pragma unroll
    for (int dt = 0; dt < 4; ++dt) {
      float4 vm4, vc4;
      vm4.x = (accm[dt][0]*sc + s_acc[l][dt*4+0]) * inv2;
      vm4.y = (accm[dt][1]*sc + s_acc[l][dt*4+1]) * inv2;
      vm4.z = (accm[dt][2]*sc + s_acc[l][dt*4+2]) * inv2;
      vm4.w = (accm[dt][3]*sc + s_acc[l][dt*4+3]) * inv2;
      vc4.x = (accc[dt][0]*sc2 + s_acc[l][16+dt*4+0]) * inv2c;
      vc4.y = (accc[dt][1]*sc2 + s_acc[l][16+dt*4+1]) * inv2c;
      vc4.z = (accc[dt][2]*sc2 + s_acc[l][16+dt*4+2]) * inv2c;
      vc4.w = (accc[dt][3]*sc2 + s_acc[l][16+dt*4+3]) * inv2c;
      if (zero) { vm4 = make_float4(0.f,0.f,0.f,0.f); vc4 = vm4; }
      *(float4*)(om_p + dt*16 + lg*4) = vm4;
      *(float4*)(oc_p + dt*16 + lg*4) = vc4;
    }
  }
}

// ---------------- output GEMM: 1-term bf16 MFMA ----------------
__global__ __launch_bounds__(256) void k_outM(float* wsf,
                                              const float* w_mean, const float* w_cov,
                                              float* outp)
{
  __shared__ __align__(16) unsigned short Ah[4096];
  __shared__ __align__(16) unsigned short Bh[4096];
  const int y = blockIdx.y;
  const float* A = wsf + (y ? WS_OC : WS_OM);
  const float* W = y ? w_cov : w_mean;
  float* out = outp + (size_t)y * 4194304ull;

  const int tid = threadIdx.x;
  const int l = tid & 63, li = l & 15, lg = l >> 4;
  const int w = tid >> 6, wr = w >> 1, wc = w & 1;
  const int blk = blockIdx.x;
  const int xcd = blk & 7, qq = blk >> 3;
  const int m0 = (xcd*8 + (qq & 7)) * 128;
  const int n0 = (qq >> 3) * 128;
  const int r0 = tid >> 2, c0 = tid & 3, r1 = r0 + 64;
  const int wo0 = r0*64 + ((c0 ^ ((r0>>1)&3))*16);
  const int wo1 = r1*64 + ((c0 ^ ((r1>>1)&3))*16);
  int roA[4], roB[4];
#pragma unroll
  for (int mi = 0; mi < 4; ++mi) {
    int r  = wr*64 + mi*16 + li;
    roA[mi] = r*64 + ((lg ^ ((r>>1)&3))*16);
    int rn = wc*64 + mi*16 + li;
    roB[mi] = rn*64 + ((lg ^ ((rn>>1)&3))*16);
  }
  const int mA0 = m0 + r0, mA1 = m0 + r1;
  const size_t abase0 = ((size_t)(mA0 >> 9) * NHEAD * SEQ + (mA0 & 511)) * DK;
  const size_t abase1 = ((size_t)(mA1 >> 9) * NHEAD * SEQ + (mA1 & 511)) * DK;
  const float* wp0 = W + (size_t)(n0 + r0)*DMODEL + c0*8;
  const float* wp1 = W + (size_t)(n0 + r1)*DMODEL + c0*8;

  auto acvt = [&](size_t abase, int k) -> uint4 {
    const float* p = A + abase + (size_t)(k >> 6) * (SEQ*DK) + (k & 63);
    return cvt8h(p);
  };

  int k0 = c0*8;
  uint4 a0 = acvt(abase0, k0);
  uint4 a1 = acvt(abase1, k0);
  uint4 b0 = cvt8h(wp0);
  uint4 b1 = cvt8h(wp1);

  f32x4 acc[4][4];
  f32x4 z = {0.f,0.f,0.f,0.f};
#pragma unroll
  for (int a = 0; a < 4; ++a)
#pragma unroll
    for (int b = 0; b < 4; ++b) acc[a][b] = z;

  for (int kt = 0; kt < DMODEL; kt += 32) {
    __syncthreads();
    *(uint4*)((char*)Ah + wo0) = a0;
    *(uint4*)((char*)Ah + wo1) = a1;
    *(uint4*)((char*)Bh + wo0) = b0;
    *(uint4*)((char*)Bh + wo1) = b1;
    __syncthreads();
    if (kt + 32 < DMODEL) {
      int kn = kt + 32 + c0*8;
      a0 = acvt(abase0, kn);
      a1 = acvt(abase1, kn);
      b0 = cvt8h(wp0 + kt + 32);
      b1 = cvt8h(wp1 + kt + 32);
    }
    bf16x8 ah[4], bh[4];
#pragma unroll
    for (int mi = 0; mi < 4; ++mi) {
      ah[mi] = *(const bf16x8*)((const char*)Ah + roA[mi]);
      bh[mi] = *(const bf16x8*)((const char*)Bh + roB[mi]);
    }
#pragma unroll
    for (int mi = 0; mi < 4; ++mi)
#pragma unroll
      for (int nj = 0; nj < 4; ++nj)
        acc[mi][nj] = MFMA32(ah[mi], bh[nj], acc[mi][nj]);
  }
#pragma unroll
  for (int mi = 0; mi < 4; ++mi)
#pragma unroll
    for (int nj = 0; nj < 4; ++nj)
#pragma unroll
      for (int reg = 0; reg < 4; ++reg) {
        int m = m0 + wr*64 + mi*16 + 4*lg + reg;
        int n = n0 + wc*64 + nj*16 + li;
        out[(size_t)m*DMODEL + n] = acc[mi][nj][reg];
      }
}

extern "C" void kernel_launch(void* const* d_in, const int* in_sizes, int n_in,
                              void* d_out, int out_size, void* d_ws, size_t ws_size,
                              hipStream_t stream) {
  (void)in_sizes; (void)n_in; (void)out_size; (void)ws_size;
  float* wsf = (float*)d_ws;

  k_gamma<<<1, 64, 0, stream>>>((const float*)d_in[14], wsf);
  k_projM<<<dim3(256, 6), 256, 0, stream>>>(
      (const float*)d_in[0], (const float*)d_in[1],
      (const float*)d_in[2], (const float*)d_in[3],
      (const float*)d_in[4], (const float*)d_in[5],
      (const float*)d_in[6], (const float*)d_in[7],
      (const float*)d_in[8], (const float*)d_in[9],
      (const float*)d_in[10], (const float*)d_in[11],
      wsf);
  k_sumAB<<<256, 256, 0, stream>>>(wsf);
  k_attn2<<<4096, 128, 0, stream>>>(wsf);
  k_outM<<<dim3(256, 2), 256, 0, stream>>>(wsf, (const float*)d_in[12],
                                           (const float*)d_in[13], (float*)d_out);
}